// Round 7
// baseline (594.403 us; speedup 1.0000x reference)
//
#include <hip/hip_runtime.h>
#include <hip/hip_bf16.h>
#include <math.h>

#define NN 50000
#define EDGES 1600000
#define ETOT (EDGES + NN)
#define FINDIM 39
#define NPART 256
#define PSZ 196        // dsts per partition; 256*196 = 50176 >= NN
#define PCAP 7100      // capacity per partition (avg 6468, +7.9 sigma)
#define P1TILE 4096

typedef __attribute__((ext_vector_type(8))) short short8;
typedef __attribute__((ext_vector_type(4))) float floatx4;

__device__ __forceinline__ unsigned pack_bf16(float a, float b) {
    __hip_bfloat162 t;
    t.x = __float2bfloat16(a);
    t.y = __float2bfloat16(b);
    return *(unsigned*)&t;
}
__device__ __forceinline__ float2 unpack_bf16(unsigned w) {
    float2 r;
    r.x = __uint_as_float(w << 16);
    r.y = __uint_as_float(w & 0xffff0000u);
    return r;
}

__device__ __forceinline__ int src_at(const int* ei, int i, bool i32) {
    return i32 ? ei[i] : ei[2 * i];
}
__device__ __forceinline__ int dst_at(const int* ei, int i, bool i32) {
    return i32 ? ei[EDGES + i] : ei[2 * (EDGES + i)];
}

// ---------------- CSR pass 1 (self-detecting int32/int64): bucket into 256 partitions ----------------
__global__ __launch_bounds__(256) void pass1_kernel(const int* __restrict__ ei,
                                                    int* __restrict__ gcursor,
                                                    unsigned* __restrict__ pbuf) {
    __shared__ unsigned raw[P1TILE];
    __shared__ unsigned srt[P1TILE];
    __shared__ int pcnt[NPART], poff[NPART], pcur[NPART], gb[NPART];
    __shared__ int i32flag;
    int t = threadIdx.x;
    if (t == 0) i32flag = 0;
    __syncthreads();
    int chunk = (ETOT + gridDim.x - 1) / gridDim.x;
    int c0 = blockIdx.x * chunk;
    int c1 = c0 + chunk; if (c1 > ETOT) c1 = ETOT;
    int sb = c0 < EDGES - 64 ? c0 : 0;
    if (t < 64 && ei[2 * (sb + t) + 1] != 0) i32flag = 1;
    __syncthreads();
    bool i32 = (i32flag != 0);
    for (int t0 = c0; t0 < c1; t0 += P1TILE) {
        int tn = c1 - t0; if (tn > P1TILE) tn = P1TILE;
        pcnt[t] = 0; pcur[t] = 0;
        __syncthreads();
        for (int i = t; i < tn; i += 256) {
            int e = t0 + i;
            int s, d;
            if (e < EDGES) { s = src_at(ei, e, i32); d = dst_at(ei, e, i32); }
            else { s = d = e - EDGES; }
            raw[i] = ((unsigned)s << 16) | (unsigned)d;
            atomicAdd(&pcnt[d / PSZ], 1);
        }
        __syncthreads();
        poff[t] = pcnt[t];
        __syncthreads();
        for (int off = 1; off < NPART; off <<= 1) {
            int v = (t >= off) ? poff[t - off] : 0;
            __syncthreads();
            poff[t] += v;
            __syncthreads();
        }
        poff[t] -= pcnt[t];                       // exclusive
        gb[t] = atomicAdd(&gcursor[t], pcnt[t]);  // global base for this tile's run
        __syncthreads();
        for (int i = t; i < tn; i += 256) {
            unsigned r = raw[i];
            int part = (int)(r & 0xFFFFu) / PSZ;
            int pos = poff[part] + atomicAdd(&pcur[part], 1);
            srt[pos] = r;
        }
        __syncthreads();
        for (int i = t; i < tn; i += 256) {
            unsigned r = srt[i];
            int part = (int)(r & 0xFFFFu) / PSZ;
            int gpos = gb[part] + (i - poff[part]);
            if (gpos < PCAP) pbuf[(size_t)part * PCAP + gpos] = r;
        }
        __syncthreads();
    }
}

// ---------------- CSR pass 2: per-partition exact sort -> rowptr + colidx (pbase inline) ----------------
__global__ __launch_bounds__(256) void pass2_kernel(const unsigned* __restrict__ pbuf,
                                                    const int* __restrict__ gcursor,
                                                    int* __restrict__ rowptr,
                                                    int* __restrict__ colidx) {
    __shared__ unsigned recs[PCAP];                 // 28.4 KB
    __shared__ int lhist[PSZ], lexcl[PSZ], lcur[PSZ];
    __shared__ int psm[NPART];
    int p = blockIdx.x;
    int t = threadIdx.x;
    // inline prefix over the 256 partition totals
    psm[t] = gcursor[t];
    __syncthreads();
    for (int off = 1; off < NPART; off <<= 1) {
        int x = (t >= off) ? psm[t - off] : 0;
        __syncthreads();
        psm[t] += x;
        __syncthreads();
    }
    int n = gcursor[p]; if (n > PCAP) n = PCAP;
    int base = psm[p] - gcursor[p];
    if (p == NPART - 1 && t == 0) rowptr[NN] = psm[NPART - 1];   // == ETOT
    int d0 = p * PSZ;
    int nd = NN - d0; if (nd > PSZ) nd = PSZ;
    if (nd < 0) nd = 0;
    for (int i = t; i < nd; i += 256) { lhist[i] = 0; lcur[i] = 0; }
    __syncthreads();
    for (int i = t; i < n; i += 256) {
        unsigned r = pbuf[(size_t)p * PCAP + i];
        recs[i] = r;
        atomicAdd(&lhist[(int)(r & 0xFFFFu) - d0], 1);
    }
    __syncthreads();
    for (int i = t; i < nd; i += 256) lexcl[i] = lhist[i];
    __syncthreads();
    for (int off = 1; off < PSZ; off <<= 1) {
        int a0 = 0;
        if (t < nd && t >= off) a0 = lexcl[t - off];
        __syncthreads();
        if (t < nd) lexcl[t] += a0;
        __syncthreads();
    }
    for (int i = t; i < nd; i += 256) {
        lexcl[i] -= lhist[i];                        // exclusive
        rowptr[d0 + i] = base + lexcl[i];
    }
    __syncthreads();
    for (int i = t; i < n; i += 256) {
        unsigned r = recs[i];
        int li = (int)(r & 0xFFFFu) - d0;
        int pos = base + lexcl[li] + atomicAdd(&lcur[li], 1);
        colidx[pos] = (int)(r >> 16);
    }
}

// ---------------- generic GEMM (K=39 encoder-1 only) ----------------
template <int NC, bool RELU>
__global__ __launch_bounds__(256) void gemm_small_kernel(const float* __restrict__ A,
                                                         const float* __restrict__ B,
                                                         const float* __restrict__ bias,
                                                         float* __restrict__ C, int M, int K) {
    constexpr int TM = 32;
    constexpr int GROUPS = 256 / NC;
    constexpr int RPG = TM / GROUPS;
    constexpr int KC = 64;
    __shared__ float As[TM * 128];
    __shared__ float Bs[KC * NC];
    int t = threadIdx.x;
    int i0 = blockIdx.x * TM;

    int rows = M - i0; if (rows > TM) rows = TM;
    for (int idx = t; idx < rows * K; idx += 256) {
        int r = idx / K, k = idx - r * K;
        As[r * K + k] = A[(size_t)(i0 + r) * K + k];
    }

    int col = t % NC, grp = t / NC;
    int rg0 = grp * RPG;
    float acc[RPG];
#pragma unroll
    for (int r = 0; r < RPG; ++r) acc[r] = 0.f;

    for (int k0 = 0; k0 < K; k0 += KC) {
        int kc = K - k0; if (kc > KC) kc = KC;
        __syncthreads();
        for (int idx = t; idx < kc * NC; idx += 256) Bs[idx] = B[(size_t)k0 * NC + idx];
        __syncthreads();
        for (int k = 0; k < kc; ++k) {
            float bv = Bs[k * NC + col];
#pragma unroll
            for (int r = 0; r < RPG; ++r) acc[r] += As[(rg0 + r) * K + k0 + k] * bv;
        }
    }

    float bb = bias ? bias[col] : 0.f;
#pragma unroll
    for (int r = 0; r < RPG; ++r) {
        int i = i0 + rg0 + r;
        if (i < M) {
            float v = acc[r] + bb;
            if (RELU) v = v > 0.f ? v : 0.f;
            C[(size_t)i * NC + col] = v;
        }
    }
}

// ---------------- fast fp32 GEMM 128x128 (enc2 only): writes h fp32 + hb packed bf16 ----------------
__global__ __launch_bounds__(256) void gemm128_kernel(const float* __restrict__ A,
                                                      const float* __restrict__ B,
                                                      const float* __restrict__ bias,
                                                      float* __restrict__ C,
                                                      unsigned* __restrict__ HB, int M) {
    __shared__ float As[64 * 32];    // 8 KB
    __shared__ float Bs[32 * 128];   // 16 KB
    int t = threadIdx.x;
    int i0 = blockIdx.x * 64;
    int tc = t & 31;
    int tr = t >> 5;
    int r0 = tr * 8;
    int c0 = tc * 4;

    float acc[8][4];
#pragma unroll
    for (int i = 0; i < 8; ++i)
#pragma unroll
        for (int j = 0; j < 4; ++j) acc[i][j] = 0.f;

    for (int k0 = 0; k0 < 128; k0 += 32) {
        __syncthreads();
#pragma unroll
        for (int q = 0; q < 2; ++q) {
            int idx = t + q * 256;
            int r = idx >> 3, kq = idx & 7;
            float4 v4 = make_float4(0.f, 0.f, 0.f, 0.f);
            if (i0 + r < M) v4 = *(const float4*)&A[(size_t)(i0 + r) * 128 + k0 + kq * 4];
            *(float4*)&As[r * 32 + kq * 4] = v4;
        }
#pragma unroll
        for (int q = 0; q < 4; ++q) {
            int idx = (t + q * 256) * 4;
            *(float4*)&Bs[idx] = *(const float4*)&B[(size_t)k0 * 128 + idx];
        }
        __syncthreads();
#pragma unroll 8
        for (int k = 0; k < 32; k += 4) {
            float4 a4[8];
#pragma unroll
            for (int i = 0; i < 8; ++i)
                a4[i] = *(const float4*)&As[(r0 + i) * 32 + k];
            float4 b4[4];
#pragma unroll
            for (int kk = 0; kk < 4; ++kk)
                b4[kk] = *(const float4*)&Bs[(k + kk) * 128 + c0];
#pragma unroll
            for (int i = 0; i < 8; ++i) {
                const float* av = (const float*)&a4[i];
#pragma unroll
                for (int kk = 0; kk < 4; ++kk) {
                    acc[i][0] += av[kk] * b4[kk].x;
                    acc[i][1] += av[kk] * b4[kk].y;
                    acc[i][2] += av[kk] * b4[kk].z;
                    acc[i][3] += av[kk] * b4[kk].w;
                }
            }
        }
    }

    float4 bias4 = *(const float4*)&bias[c0];
#pragma unroll
    for (int i = 0; i < 8; ++i) {
        int row = i0 + r0 + i;
        if (row < M) {
            float4 o;
            o.x = acc[i][0] + bias4.x;
            o.y = acc[i][1] + bias4.y;
            o.z = acc[i][2] + bias4.z;
            o.w = acc[i][3] + bias4.w;
            *(float4*)&C[(size_t)row * 128 + c0] = o;
            uint2 p;
            p.x = pack_bf16(o.x, o.y);
            p.y = pack_bf16(o.z, o.w);
            *(uint2*)&HB[(size_t)row * 64 + tc * 2] = p;
        }
    }
}

// ---------------- W -> bf16 transposed copy: wtb[c][k] = bf16(W[k][c]) ----------------
__global__ __launch_bounds__(256) void wconv_kernel(const float* __restrict__ W,
                                                    unsigned short* __restrict__ wtb) {
    int idx = blockIdx.x * 256 + threadIdx.x;   // grid 64 -> 16384
    int c = idx >> 7, k = idx & 127;
    unsigned p = pack_bf16(W[(size_t)k * 128 + c], 0.f);
    wtb[(size_t)c * 128 + k] = (unsigned short)(p & 0xffffu);
}

// ---------------- MFMA bf16 GEMM: xp = hb @ W  (M x 128 x 128), epilogue xpk + exp'd es/ed.
// Per block: 4 waves x 16 rows. Per wave: 8 N-tiles x 4 K-chunks of mfma_f32_16x16x32_bf16.
// A frag: lane holds row (l&15), k = kc*32 + (l>>4)*8 + j  (16B from hb, packed bf16 pairs).
// B frag: lane holds col (l&15), same k grouping (16B from wtb[col][k]) — A/B k-order only
// needs mutual consistency. D layout (verified): col = l&15 (+16n), row = (l>>4)*4 + reg.
__global__ __launch_bounds__(256) void gemm_mfma_kernel(const unsigned* __restrict__ hb,
                                                        const unsigned short* __restrict__ wtb,
                                                        unsigned* __restrict__ XP,
                                                        const float* __restrict__ a_s,
                                                        const float* __restrict__ a_d,
                                                        float* __restrict__ esx,
                                                        float* __restrict__ edx, int M) {
    int t = threadIdx.x;
    int w = t >> 6, l = t & 63;
    int c = l & 15, grp = l >> 4;
    int i0 = blockIdx.x * 64 + w * 16;
    int arow = i0 + c;

    floatx4 acc[8];
#pragma unroll
    for (int n = 0; n < 8; ++n) acc[n] = (floatx4){0.f, 0.f, 0.f, 0.f};

    uint4 a4[4];
#pragma unroll
    for (int kc = 0; kc < 4; ++kc) {
        uint4 z = make_uint4(0u, 0u, 0u, 0u);
        if (arow < M) z = *(const uint4*)&hb[(size_t)arow * 64 + (kc << 4) + (grp << 2)];
        a4[kc] = z;
    }

#pragma unroll
    for (int kc = 0; kc < 4; ++kc) {
        short8 af = *(short8*)&a4[kc];
#pragma unroll
        for (int n = 0; n < 8; ++n) {
            short8 bf = *(const short8*)&wtb[(size_t)(((n << 4) + c) * 128 + (kc << 5) + (grp << 3))];
            acc[n] = __builtin_amdgcn_mfma_f32_16x16x32_bf16(af, bf, acc[n], 0, 0, 0);
        }
    }

    // ---- epilogue: rows i0 + grp*4 + r, col n*16 + c
    float asv[8], adv[8];
#pragma unroll
    for (int n = 0; n < 8; ++n) { asv[n] = a_s[(n << 4) + c]; adv[n] = a_d[(n << 4) + c]; }

    float sp[4][4], dp[4][4];   // [r][head]
#pragma unroll
    for (int r = 0; r < 4; ++r)
#pragma unroll
        for (int hd = 0; hd < 4; ++hd) { sp[r][hd] = 0.f; dp[r][hd] = 0.f; }

#pragma unroll
    for (int n = 0; n < 8; ++n) {
#pragma unroll
        for (int r = 0; r < 4; ++r) {
            float vv = acc[n][r];
            float pv = __shfl_xor(vv, 1);
            int row = i0 + (grp << 2) + r;
            if (!(c & 1) && row < M)
                XP[(size_t)row * 64 + (n << 3) + (c >> 1)] = pack_bf16(vv, pv);
            sp[r][n >> 1] = fmaf(vv, asv[n], sp[r][n >> 1]);
            dp[r][n >> 1] = fmaf(vv, adv[n], dp[r][n >> 1]);
        }
    }
#pragma unroll
    for (int r = 0; r < 4; ++r)
#pragma unroll
        for (int hd = 0; hd < 4; ++hd) {
            float s = sp[r][hd], d = dp[r][hd];
#pragma unroll
            for (int off = 1; off <= 8; off <<= 1) {
                s += __shfl_xor(s, off);
                d += __shfl_xor(d, off);
            }
            sp[r][hd] = s; dp[r][hd] = d;
        }
    if (c < 4) {
#pragma unroll
        for (int r = 0; r < 4; ++r) {
            int row = i0 + (grp << 2) + r;
            if (row < M) {
                float s = (c == 0) ? sp[r][0] : (c == 1) ? sp[r][1] : (c == 2) ? sp[r][2] : sp[r][3];
                float d = (c == 0) ? dp[r][0] : (c == 1) ? dp[r][1] : (c == 2) ? dp[r][2] : dp[r][3];
                float2 E, F;
                E.x = __expf(s); E.y = __expf(0.2f * s);
                F.x = __expf(d); F.y = __expf(0.2f * d);
                *(float2*)&esx[(size_t)row * 8 + (c << 1)] = E;
                *(float2*)&edx[(size_t)row * 8 + (c << 1)] = F;
            }
        }
    }
}

// ---------------- head GEMMs fully fused: h -> out (impact+timing), 24KB LDS ----------------
__global__ __launch_bounds__(256) void gemm_heads_kernel(const float* __restrict__ A,
                                                         const float* __restrict__ iw1,
                                                         const float* __restrict__ ib1,
                                                         const float* __restrict__ tw1,
                                                         const float* __restrict__ tb1,
                                                         const float* __restrict__ iw2,
                                                         const float* __restrict__ ib2,
                                                         const float* __restrict__ tw2,
                                                         const float* __restrict__ tb2,
                                                         float* __restrict__ out, int M) {
    __shared__ float As[64 * 32];
    __shared__ float Bs[32 * 128];
    int t = threadIdx.x;
    int i0 = blockIdx.x * 64;
    int tc = t & 31;
    int tr = t >> 5;
    int r0 = tr * 8;
    int c0 = tc * 4;                 // virtual col (0-63 impact, 64-127 timing)

    float acc[8][4];
#pragma unroll
    for (int i = 0; i < 8; ++i)
#pragma unroll
        for (int j = 0; j < 4; ++j) acc[i][j] = 0.f;

    for (int k0 = 0; k0 < 128; k0 += 32) {
        __syncthreads();
#pragma unroll
        for (int q = 0; q < 2; ++q) {
            int idx = t + q * 256;
            int r = idx >> 3, kq = idx & 7;
            float4 v4 = make_float4(0.f, 0.f, 0.f, 0.f);
            if (i0 + r < M) v4 = *(const float4*)&A[(size_t)(i0 + r) * 128 + k0 + kq * 4];
            *(float4*)&As[r * 32 + kq * 4] = v4;
        }
#pragma unroll
        for (int q = 0; q < 4; ++q) {
            int idx = (t + q * 256) * 4;       // flat into [32][128]
            int k = idx >> 7, cl = idx & 127;
            float4 v4 = (cl < 64)
                ? *(const float4*)&iw1[(size_t)(k0 + k) * 64 + cl]
                : *(const float4*)&tw1[(size_t)(k0 + k) * 64 + (cl - 64)];
            *(float4*)&Bs[idx] = v4;
        }
        __syncthreads();
#pragma unroll 8
        for (int k = 0; k < 32; k += 4) {
            float4 a4[8];
#pragma unroll
            for (int i = 0; i < 8; ++i)
                a4[i] = *(const float4*)&As[(r0 + i) * 32 + k];
            float4 b4[4];
#pragma unroll
            for (int kk = 0; kk < 4; ++kk)
                b4[kk] = *(const float4*)&Bs[(k + kk) * 128 + c0];
#pragma unroll
            for (int i = 0; i < 8; ++i) {
                const float* av = (const float*)&a4[i];
#pragma unroll
                for (int kk = 0; kk < 4; ++kk) {
                    acc[i][0] += av[kk] * b4[kk].x;
                    acc[i][1] += av[kk] * b4[kk].y;
                    acc[i][2] += av[kk] * b4[kk].z;
                    acc[i][3] += av[kk] * b4[kk].w;
                }
            }
        }
    }

    bool isimp = (tc < 16);
    int lc = isimp ? c0 : (c0 - 64);
    float v[8][4];
#pragma unroll
    for (int i = 0; i < 8; ++i)
#pragma unroll
        for (int j = 0; j < 4; ++j) {
            float b = isimp ? ib1[lc + j] : tb1[lc + j];
            float x = acc[i][j] + b;
            v[i][j] = x > 0.f ? x : 0.f;
        }
#pragma unroll
    for (int i = 0; i < 8; ++i) {
        int row = i0 + r0 + i;
        if (isimp) {
#pragma unroll
            for (int c = 0; c < 3; ++c) {
                float pc = v[i][0] * iw2[(lc + 0) * 3 + c] + v[i][1] * iw2[(lc + 1) * 3 + c]
                         + v[i][2] * iw2[(lc + 2) * 3 + c] + v[i][3] * iw2[(lc + 3) * 3 + c];
#pragma unroll
                for (int off = 8; off >= 1; off >>= 1) pc += __shfl_xor(pc, off);
                if (tc == 0 && row < M) out[(size_t)row * 3 + c] = pc + ib2[c];
            }
        } else {
#pragma unroll
            for (int d = 0; d < 2; ++d) {
                float pd = v[i][0] * tw2[(lc + 0) * 2 + d] + v[i][1] * tw2[(lc + 1) * 2 + d]
                         + v[i][2] * tw2[(lc + 2) * 2 + d] + v[i][3] * tw2[(lc + 3) * 2 + d];
#pragma unroll
                for (int off = 8; off >= 1; off >>= 1) pd += __shfl_xor(pd, off);
                if (tc == 16 && row < M) {
                    float a = pd + tb2[d];
                    float sp = a > 20.f ? a : log1pf(__expf(a));
                    out[(size_t)(NN * 3) + (size_t)row * 2 + d] = sp;
                }
            }
        }
    }
}

// ---------------- gat v13: v10 structure (2 nodes/wave, 32 lanes/node, uint2 gathers,
// 8-deep MLP, no LDS) + exp-free weights (v12-proven): w = max(E1*F1, E2*F2) with
// E=(exp(es),exp(0.2es)) gathered, F=(exp(ed),exp(0.2ed)) per node. Epilogue also
// writes hb (packed bf16 h) to feed the next layer's MFMA GEMM.
__global__ __launch_bounds__(256, 6) void gat_kernel(const unsigned* __restrict__ xpk,
                                                     const float* __restrict__ esx,
                                                     const float* __restrict__ edx,
                                                     const int* __restrict__ rowptr,
                                                     const int* __restrict__ colidx,
                                                     float* __restrict__ h,   // in-out (residual)
                                                     unsigned* __restrict__ hb, // bf16 copy out (nullable)
                                                     const float* __restrict__ bc,
                                                     const float* __restrict__ g,
                                                     const float* __restrict__ be) {
    int wv = threadIdx.x >> 6, l = threadIdx.x & 63;
    int hf = l >> 5;                        // which node of the pair
    int lh = l & 31;
    int hd = lh >> 3;                       // head 0..3
    int j  = lh & 7;                        // 0..7
    int v = blockIdx.x * 8 + wv * 2 + hf;   // 6250*8 = 50000 exact
    if (v >= NN) return;                    // defensive
    int s0 = rowptr[v], s1 = rowptr[v + 1];
    int len = s1 - s0;                      // >= 1 (self-loop)
    int nmax = max(len, __shfl_xor(len, 32));
    int c0 = (hd << 5) + (j << 2);          // 4 channels owned by this lane
    int xsel = (hd << 4) + (j << 1);        // even dword index into 64-dword xpk row
    float2 F = *(const float2*)&edx[((unsigned)v << 3) + (hd << 1)];

    // hoisted: residual row load overlaps the whole gather loop
    float4 h4 = *(const float4*)&h[(size_t)v * 128 + c0];

    float a0 = 0.f, a1 = 0.f, a2 = 0.f, a3 = 0.f, den = 0.f;
    for (int p8 = 0; p8 < nmax; p8 += 8) {
        int u[8];
#pragma unroll
        for (int q = 0; q < 8; ++q) {
            int idx = p8 + q;
            u[q] = colidx[s0 + (idx < len ? idx : len - 1)];   // clamp: always valid mem
        }
        float2 E[8];
#pragma unroll
        for (int q = 0; q < 8; ++q)
            E[q] = *(const float2*)&esx[((unsigned)u[q] << 3) + (hd << 1)];
        uint2 xw[8];
#pragma unroll
        for (int q = 0; q < 8; ++q)
            xw[q] = *(const uint2*)&xpk[((unsigned)u[q] << 6) + xsel];
        float w[8];
#pragma unroll
        for (int q = 0; q < 8; ++q) {
            float ww = fmaxf(E[q].x * F.x, E[q].y * F.y);   // exp(leaky(es+ed))
            w[q] = (p8 + q < len) ? ww : 0.f;
            den += w[q];
        }
#pragma unroll
        for (int q = 0; q < 8; ++q) {
            float2 x0 = unpack_bf16(xw[q].x);
            float2 x1 = unpack_bf16(xw[q].y);
            a0 = fmaf(w[q], x0.x, a0);
            a1 = fmaf(w[q], x0.y, a1);
            a2 = fmaf(w[q], x1.x, a2);
            a3 = fmaf(w[q], x1.y, a3);
        }
    }
    float rd = 1.f / den;

    // ---- epilogue: residual + LN + relu; reductions within the 32-lane half.
    float4 bc4 = *(const float4*)&bc[c0];
    float y0 = a0 * rd + bc4.x + h4.x;
    float y1 = a1 * rd + bc4.y + h4.y;
    float y2 = a2 * rd + bc4.z + h4.z;
    float y3 = a3 * rd + bc4.w + h4.w;

    float s = y0 + y1 + y2 + y3;
#pragma unroll
    for (int off = 16; off >= 1; off >>= 1) s += __shfl_xor(s, off);
    float mean = s * (1.f / 128.f);
    float d0 = y0 - mean, d1 = y1 - mean, d2 = y2 - mean, d3 = y3 - mean;
    float vv = d0 * d0 + d1 * d1 + d2 * d2 + d3 * d3;
#pragma unroll
    for (int off = 16; off >= 1; off >>= 1) vv += __shfl_xor(vv, off);
    float rstd = rsqrtf(vv * (1.f / 128.f) + 1e-5f);
    float4 g4  = *(const float4*)&g[c0];
    float4 be4 = *(const float4*)&be[c0];
    float z0 = d0 * rstd * g4.x + be4.x;
    float z1 = d1 * rstd * g4.y + be4.y;
    float z2 = d2 * rstd * g4.z + be4.z;
    float z3 = d3 * rstd * g4.w + be4.w;
    float4 o;
    o.x = z0 > 0.f ? z0 : 0.f;
    o.y = z1 > 0.f ? z1 : 0.f;
    o.z = z2 > 0.f ? z2 : 0.f;
    o.w = z3 > 0.f ? z3 : 0.f;
    *(float4*)&h[(size_t)v * 128 + c0] = o;
    if (hb) {
        uint2 hp;
        hp.x = pack_bf16(o.x, o.y);
        hp.y = pack_bf16(o.z, o.w);
        *(uint2*)&hb[(size_t)v * 64 + (c0 >> 1)] = hp;
    }
}

extern "C" void kernel_launch(void* const* d_in, const int* in_sizes, int n_in,
                              void* d_out, int out_size, void* d_ws, size_t ws_size,
                              hipStream_t stream) {
    const float* x      = (const float*)d_in[0];
    const int*   ei     = (const int*)d_in[1];
    const float* enc_w1 = (const float*)d_in[2];
    const float* enc_b1 = (const float*)d_in[3];
    const float* enc_w2 = (const float*)d_in[4];
    const float* enc_b2 = (const float*)d_in[5];
    const float *W[3], *as_[3], *ad_[3], *bc[3], *g[3], *be[3];
    for (int l = 0; l < 3; ++l) {
        W[l]   = (const float*)d_in[6 + l * 6 + 0];
        as_[l] = (const float*)d_in[6 + l * 6 + 1];
        ad_[l] = (const float*)d_in[6 + l * 6 + 2];
        bc[l]  = (const float*)d_in[6 + l * 6 + 3];
        g[l]   = (const float*)d_in[6 + l * 6 + 4];
        be[l]  = (const float*)d_in[6 + l * 6 + 5];
    }
    const float* imp_w1 = (const float*)d_in[24];
    const float* imp_b1 = (const float*)d_in[25];
    const float* imp_w2 = (const float*)d_in[26];
    const float* imp_b2 = (const float*)d_in[27];
    const float* tim_w1 = (const float*)d_in[28];
    const float* tim_b1 = (const float*)d_in[29];
    const float* tim_w2 = (const float*)d_in[30];
    const float* tim_b2 = (const float*)d_in[31];

    int* gcursor = (int*)d_ws;               // NPART
    int* rowptr  = gcursor + NPART + 64;     // NN+1
    int* colidx  = rowptr + NN + 1;          // ETOT (+8 slack)
    uintptr_t pb = (uintptr_t)(colidx + ETOT + 8);
    pb = (pb + 255) & ~(uintptr_t)255;
    unsigned* pbuf = (unsigned*)pb;          // NPART*PCAP (7.3 MB)
    uintptr_t fb = (uintptr_t)(pbuf + (size_t)NPART * PCAP);
    fb = (fb + 255) & ~(uintptr_t)255;
    float* esx = (float*)fb;                 // NN*8 (E1,E2 per head)
    float* edx = esx + (size_t)NN * 8;       // NN*8 (F1,F2 per head)
    float* h   = edx + (size_t)NN * 8;       // NN*128 fp32 (also enc1 tmp: block-local RAW safe)
    float* xpf = h + (size_t)NN * 128;       // region sized NN*128 floats
    unsigned* xpk = (unsigned*)xpf;                       // first half: packed bf16 xp
    unsigned* hb  = (unsigned*)(xpf + (size_t)NN * 64);   // second half: packed bf16 h
    unsigned short* wtb = (unsigned short*)(xpf + (size_t)NN * 128); // 3 x 16384 bf16
    float* tmp = h;                          // enc1 scratch aliases h (RAW is block-local in enc2)

    hipMemsetAsync(gcursor, 0, NPART * sizeof(int), stream);
    pass1_kernel<<<512, 256, 0, stream>>>(ei, gcursor, pbuf);
    pass2_kernel<<<NPART, 256, 0, stream>>>(pbuf, gcursor, rowptr, colidx);
    for (int l = 0; l < 3; ++l)
        wconv_kernel<<<64, 256, 0, stream>>>(W[l], wtb + (size_t)l * 16384);

    const int GB64 = (NN + 63) / 64;
    gemm_small_kernel<128, true><<<(NN + 31) / 32, 256, 0, stream>>>(x, enc_w1, enc_b1, tmp, NN, FINDIM);
    gemm128_kernel<<<GB64, 256, 0, stream>>>(tmp, enc_w2, enc_b2, h, hb, NN);

    for (int l = 0; l < 3; ++l) {
        gemm_mfma_kernel<<<GB64, 256, 0, stream>>>(hb, wtb + (size_t)l * 16384, xpk,
                                                   as_[l], ad_[l], esx, edx, NN);
        gat_kernel<<<(NN + 7) / 8, 256, 0, stream>>>(xpk, esx, edx, rowptr, colidx, h,
                                                     (l < 2) ? hb : nullptr,
                                                     bc[l], g[l], be[l]);
    }

    gemm_heads_kernel<<<GB64, 256, 0, stream>>>(h, imp_w1, imp_b1, tim_w1, tim_b1,
                                                imp_w2, imp_b2, tim_w2, tim_b2,
                                                (float*)d_out, NN);
}

// Round 8
// 546.756 us; speedup vs baseline: 1.0871x; 1.0871x over previous
//
#include <hip/hip_runtime.h>
#include <hip/hip_bf16.h>
#include <math.h>

#define NN 50000
#define EDGES 1600000
#define ETOT (EDGES + NN)
#define FINDIM 39
#define NPART 256
#define PSZ 196        // dsts per partition; 256*196 = 50176 >= NN
#define PCAP 7100      // capacity per partition (avg 6468, +7.9 sigma)
#define P1TILE 4096

typedef __attribute__((ext_vector_type(8))) short short8;
typedef __attribute__((ext_vector_type(4))) float floatx4;

__device__ __forceinline__ unsigned pack_bf16(float a, float b) {
    __hip_bfloat162 t;
    t.x = __float2bfloat16(a);
    t.y = __float2bfloat16(b);
    return *(unsigned*)&t;
}
__device__ __forceinline__ float2 unpack_bf16(unsigned w) {
    float2 r;
    r.x = __uint_as_float(w << 16);
    r.y = __uint_as_float(w & 0xffff0000u);
    return r;
}

__device__ __forceinline__ int src_at(const int* ei, int i, bool i32) {
    return i32 ? ei[i] : ei[2 * i];
}
__device__ __forceinline__ int dst_at(const int* ei, int i, bool i32) {
    return i32 ? ei[EDGES + i] : ei[2 * (EDGES + i)];
}

// ---------------- CSR pass 1 (self-detecting int32/int64): bucket into 256 partitions ----------------
__global__ __launch_bounds__(256) void pass1_kernel(const int* __restrict__ ei,
                                                    int* __restrict__ gcursor,
                                                    unsigned* __restrict__ pbuf) {
    __shared__ unsigned raw[P1TILE];
    __shared__ unsigned srt[P1TILE];
    __shared__ int pcnt[NPART], poff[NPART], pcur[NPART], gb[NPART];
    __shared__ int i32flag;
    int t = threadIdx.x;
    if (t == 0) i32flag = 0;
    __syncthreads();
    int chunk = (ETOT + gridDim.x - 1) / gridDim.x;
    int c0 = blockIdx.x * chunk;
    int c1 = c0 + chunk; if (c1 > ETOT) c1 = ETOT;
    int sb = c0 < EDGES - 64 ? c0 : 0;
    if (t < 64 && ei[2 * (sb + t) + 1] != 0) i32flag = 1;
    __syncthreads();
    bool i32 = (i32flag != 0);
    for (int t0 = c0; t0 < c1; t0 += P1TILE) {
        int tn = c1 - t0; if (tn > P1TILE) tn = P1TILE;
        pcnt[t] = 0; pcur[t] = 0;
        __syncthreads();
        for (int i = t; i < tn; i += 256) {
            int e = t0 + i;
            int s, d;
            if (e < EDGES) { s = src_at(ei, e, i32); d = dst_at(ei, e, i32); }
            else { s = d = e - EDGES; }
            raw[i] = ((unsigned)s << 16) | (unsigned)d;
            atomicAdd(&pcnt[d / PSZ], 1);
        }
        __syncthreads();
        poff[t] = pcnt[t];
        __syncthreads();
        for (int off = 1; off < NPART; off <<= 1) {
            int v = (t >= off) ? poff[t - off] : 0;
            __syncthreads();
            poff[t] += v;
            __syncthreads();
        }
        poff[t] -= pcnt[t];                       // exclusive
        gb[t] = atomicAdd(&gcursor[t], pcnt[t]);  // global base for this tile's run
        __syncthreads();
        for (int i = t; i < tn; i += 256) {
            unsigned r = raw[i];
            int part = (int)(r & 0xFFFFu) / PSZ;
            int pos = poff[part] + atomicAdd(&pcur[part], 1);
            srt[pos] = r;
        }
        __syncthreads();
        for (int i = t; i < tn; i += 256) {
            unsigned r = srt[i];
            int part = (int)(r & 0xFFFFu) / PSZ;
            int gpos = gb[part] + (i - poff[part]);
            if (gpos < PCAP) pbuf[(size_t)part * PCAP + gpos] = r;
        }
        __syncthreads();
    }
}

// ---------------- CSR pass 2: per-partition exact sort -> rowptr + colidx (pbase inline) ----------------
__global__ __launch_bounds__(256) void pass2_kernel(const unsigned* __restrict__ pbuf,
                                                    const int* __restrict__ gcursor,
                                                    int* __restrict__ rowptr,
                                                    int* __restrict__ colidx) {
    __shared__ unsigned recs[PCAP];                 // 28.4 KB
    __shared__ int lhist[PSZ], lexcl[PSZ], lcur[PSZ];
    __shared__ int psm[NPART];
    int p = blockIdx.x;
    int t = threadIdx.x;
    // inline prefix over the 256 partition totals
    psm[t] = gcursor[t];
    __syncthreads();
    for (int off = 1; off < NPART; off <<= 1) {
        int x = (t >= off) ? psm[t - off] : 0;
        __syncthreads();
        psm[t] += x;
        __syncthreads();
    }
    int n = gcursor[p]; if (n > PCAP) n = PCAP;
    int base = psm[p] - gcursor[p];
    if (p == NPART - 1 && t == 0) rowptr[NN] = psm[NPART - 1];   // == ETOT
    int d0 = p * PSZ;
    int nd = NN - d0; if (nd > PSZ) nd = PSZ;
    if (nd < 0) nd = 0;
    for (int i = t; i < nd; i += 256) { lhist[i] = 0; lcur[i] = 0; }
    __syncthreads();
    for (int i = t; i < n; i += 256) {
        unsigned r = pbuf[(size_t)p * PCAP + i];
        recs[i] = r;
        atomicAdd(&lhist[(int)(r & 0xFFFFu) - d0], 1);
    }
    __syncthreads();
    for (int i = t; i < nd; i += 256) lexcl[i] = lhist[i];
    __syncthreads();
    for (int off = 1; off < PSZ; off <<= 1) {
        int a0 = 0;
        if (t < nd && t >= off) a0 = lexcl[t - off];
        __syncthreads();
        if (t < nd) lexcl[t] += a0;
        __syncthreads();
    }
    for (int i = t; i < nd; i += 256) {
        lexcl[i] -= lhist[i];                        // exclusive
        rowptr[d0 + i] = base + lexcl[i];
    }
    __syncthreads();
    for (int i = t; i < n; i += 256) {
        unsigned r = recs[i];
        int li = (int)(r & 0xFFFFu) - d0;
        int pos = base + lexcl[li] + atomicAdd(&lcur[li], 1);
        colidx[pos] = (int)(r >> 16);
    }
}

// ---------------- generic GEMM (K=39 encoder-1 only) ----------------
template <int NC, bool RELU>
__global__ __launch_bounds__(256) void gemm_small_kernel(const float* __restrict__ A,
                                                         const float* __restrict__ B,
                                                         const float* __restrict__ bias,
                                                         float* __restrict__ C, int M, int K) {
    constexpr int TM = 32;
    constexpr int GROUPS = 256 / NC;
    constexpr int RPG = TM / GROUPS;
    constexpr int KC = 64;
    __shared__ float As[TM * 128];
    __shared__ float Bs[KC * NC];
    int t = threadIdx.x;
    int i0 = blockIdx.x * TM;

    int rows = M - i0; if (rows > TM) rows = TM;
    for (int idx = t; idx < rows * K; idx += 256) {
        int r = idx / K, k = idx - r * K;
        As[r * K + k] = A[(size_t)(i0 + r) * K + k];
    }

    int col = t % NC, grp = t / NC;
    int rg0 = grp * RPG;
    float acc[RPG];
#pragma unroll
    for (int r = 0; r < RPG; ++r) acc[r] = 0.f;

    for (int k0 = 0; k0 < K; k0 += KC) {
        int kc = K - k0; if (kc > KC) kc = KC;
        __syncthreads();
        for (int idx = t; idx < kc * NC; idx += 256) Bs[idx] = B[(size_t)k0 * NC + idx];
        __syncthreads();
        for (int k = 0; k < kc; ++k) {
            float bv = Bs[k * NC + col];
#pragma unroll
            for (int r = 0; r < RPG; ++r) acc[r] += As[(rg0 + r) * K + k0 + k] * bv;
        }
    }

    float bb = bias ? bias[col] : 0.f;
#pragma unroll
    for (int r = 0; r < RPG; ++r) {
        int i = i0 + rg0 + r;
        if (i < M) {
            float v = acc[r] + bb;
            if (RELU) v = v > 0.f ? v : 0.f;
            C[(size_t)i * NC + col] = v;
        }
    }
}

// ---------------- fast fp32 GEMM 128x128 (enc2 only) ----------------
__global__ __launch_bounds__(256) void gemm128_kernel(const float* __restrict__ A,
                                                      const float* __restrict__ B,
                                                      const float* __restrict__ bias,
                                                      float* __restrict__ C, int M) {
    __shared__ float As[64 * 32];    // 8 KB
    __shared__ float Bs[32 * 128];   // 16 KB
    int t = threadIdx.x;
    int i0 = blockIdx.x * 64;
    int tc = t & 31;
    int tr = t >> 5;
    int r0 = tr * 8;
    int c0 = tc * 4;

    float acc[8][4];
#pragma unroll
    for (int i = 0; i < 8; ++i)
#pragma unroll
        for (int j = 0; j < 4; ++j) acc[i][j] = 0.f;

    for (int k0 = 0; k0 < 128; k0 += 32) {
        __syncthreads();
#pragma unroll
        for (int q = 0; q < 2; ++q) {
            int idx = t + q * 256;
            int r = idx >> 3, kq = idx & 7;
            float4 v4 = make_float4(0.f, 0.f, 0.f, 0.f);
            if (i0 + r < M) v4 = *(const float4*)&A[(size_t)(i0 + r) * 128 + k0 + kq * 4];
            *(float4*)&As[r * 32 + kq * 4] = v4;
        }
#pragma unroll
        for (int q = 0; q < 4; ++q) {
            int idx = (t + q * 256) * 4;
            *(float4*)&Bs[idx] = *(const float4*)&B[(size_t)k0 * 128 + idx];
        }
        __syncthreads();
#pragma unroll 8
        for (int k = 0; k < 32; k += 4) {
            float4 a4[8];
#pragma unroll
            for (int i = 0; i < 8; ++i)
                a4[i] = *(const float4*)&As[(r0 + i) * 32 + k];
            float4 b4[4];
#pragma unroll
            for (int kk = 0; kk < 4; ++kk)
                b4[kk] = *(const float4*)&Bs[(k + kk) * 128 + c0];
#pragma unroll
            for (int i = 0; i < 8; ++i) {
                const float* av = (const float*)&a4[i];
#pragma unroll
                for (int kk = 0; kk < 4; ++kk) {
                    acc[i][0] += av[kk] * b4[kk].x;
                    acc[i][1] += av[kk] * b4[kk].y;
                    acc[i][2] += av[kk] * b4[kk].z;
                    acc[i][3] += av[kk] * b4[kk].w;
                }
            }
        }
    }

    float4 bias4 = *(const float4*)&bias[c0];
#pragma unroll
    for (int i = 0; i < 8; ++i) {
        int row = i0 + r0 + i;
        if (row < M) {
            float4 o;
            o.x = acc[i][0] + bias4.x;
            o.y = acc[i][1] + bias4.y;
            o.z = acc[i][2] + bias4.z;
            o.w = acc[i][3] + bias4.w;
            *(float4*)&C[(size_t)row * 128 + c0] = o;
        }
    }
}

// ---------------- W -> bf16 transposed copy: wtb[c][k] = bf16(W[k][c]) ----------------
__global__ __launch_bounds__(256) void wconv_kernel(const float* __restrict__ W,
                                                    unsigned short* __restrict__ wtb) {
    int idx = blockIdx.x * 256 + threadIdx.x;   // grid 64 -> 16384
    int c = idx >> 7, k = idx & 127;
    unsigned p = pack_bf16(W[(size_t)k * 128 + c], 0.f);
    wtb[(size_t)c * 128 + k] = (unsigned short)(p & 0xffffu);
}

// ---------------- MFMA bf16 GEMM: xp = bf16(h) @ W  (M x 128 x 128).
// Reads fp32 h, converts A-frags in-register (2 float4 + 4 cvt_pk per k-chunk).
// Epilogue: packed-bf16 xpk + raw es/ed scalars (v10 format, exp stays in gat).
// D layout (verified m89/m91): col = l&15 (+16n), row = (l>>4)*4 + reg.
__global__ __launch_bounds__(256) void gemm_mfma_kernel(const float* __restrict__ H,
                                                        const unsigned short* __restrict__ wtb,
                                                        unsigned* __restrict__ XP,
                                                        const float* __restrict__ a_s,
                                                        const float* __restrict__ a_d,
                                                        float* __restrict__ es,
                                                        float* __restrict__ ed, int M) {
    int t = threadIdx.x;
    int w = t >> 6, l = t & 63;
    int c = l & 15, grp = l >> 4;
    int i0 = blockIdx.x * 64 + w * 16;
    int arow = i0 + c;

    floatx4 acc[8];
#pragma unroll
    for (int n = 0; n < 8; ++n) acc[n] = (floatx4){0.f, 0.f, 0.f, 0.f};

    short8 af[4];
#pragma unroll
    for (int kc = 0; kc < 4; ++kc) {
        float4 f0 = make_float4(0.f, 0.f, 0.f, 0.f), f1 = f0;
        if (arow < M) {
            const float* hp = &H[(size_t)arow * 128 + (kc << 5) + (grp << 3)];
            f0 = *(const float4*)hp;
            f1 = *(const float4*)(hp + 4);
        }
        unsigned pk[4];
        pk[0] = pack_bf16(f0.x, f0.y);
        pk[1] = pack_bf16(f0.z, f0.w);
        pk[2] = pack_bf16(f1.x, f1.y);
        pk[3] = pack_bf16(f1.z, f1.w);
        af[kc] = *(short8*)pk;
    }

#pragma unroll
    for (int kc = 0; kc < 4; ++kc) {
#pragma unroll
        for (int n = 0; n < 8; ++n) {
            short8 bf = *(const short8*)&wtb[(size_t)(((n << 4) + c) * 128 + (kc << 5) + (grp << 3))];
            acc[n] = __builtin_amdgcn_mfma_f32_16x16x32_bf16(af[kc], bf, acc[n], 0, 0, 0);
        }
    }

    // ---- epilogue: rows i0 + grp*4 + r, col n*16 + c
    float asv[8], adv[8];
#pragma unroll
    for (int n = 0; n < 8; ++n) { asv[n] = a_s[(n << 4) + c]; adv[n] = a_d[(n << 4) + c]; }

    float sp[4][4], dp[4][4];   // [r][head]
#pragma unroll
    for (int r = 0; r < 4; ++r)
#pragma unroll
        for (int hd = 0; hd < 4; ++hd) { sp[r][hd] = 0.f; dp[r][hd] = 0.f; }

#pragma unroll
    for (int n = 0; n < 8; ++n) {
#pragma unroll
        for (int r = 0; r < 4; ++r) {
            float vv = acc[n][r];
            float pv = __shfl_xor(vv, 1);
            int row = i0 + (grp << 2) + r;
            if (!(c & 1) && row < M)
                XP[(size_t)row * 64 + (n << 3) + (c >> 1)] = pack_bf16(vv, pv);
            sp[r][n >> 1] = fmaf(vv, asv[n], sp[r][n >> 1]);
            dp[r][n >> 1] = fmaf(vv, adv[n], dp[r][n >> 1]);
        }
    }
#pragma unroll
    for (int r = 0; r < 4; ++r)
#pragma unroll
        for (int hd = 0; hd < 4; ++hd) {
            float s = sp[r][hd], d = dp[r][hd];
#pragma unroll
            for (int off = 1; off <= 8; off <<= 1) {
                s += __shfl_xor(s, off);
                d += __shfl_xor(d, off);
            }
            sp[r][hd] = s; dp[r][hd] = d;
        }
    if (c < 4) {
#pragma unroll
        for (int r = 0; r < 4; ++r) {
            int row = i0 + (grp << 2) + r;
            if (row < M) {
                float s = (c == 0) ? sp[r][0] : (c == 1) ? sp[r][1] : (c == 2) ? sp[r][2] : sp[r][3];
                float d = (c == 0) ? dp[r][0] : (c == 1) ? dp[r][1] : (c == 2) ? dp[r][2] : dp[r][3];
                es[(size_t)row * 4 + c] = s;
                ed[(size_t)row * 4 + c] = d;
            }
        }
    }
}

// ---------------- head GEMMs fully fused: h -> out (impact+timing), 24KB LDS ----------------
__global__ __launch_bounds__(256) void gemm_heads_kernel(const float* __restrict__ A,
                                                         const float* __restrict__ iw1,
                                                         const float* __restrict__ ib1,
                                                         const float* __restrict__ tw1,
                                                         const float* __restrict__ tb1,
                                                         const float* __restrict__ iw2,
                                                         const float* __restrict__ ib2,
                                                         const float* __restrict__ tw2,
                                                         const float* __restrict__ tb2,
                                                         float* __restrict__ out, int M) {
    __shared__ float As[64 * 32];
    __shared__ float Bs[32 * 128];
    int t = threadIdx.x;
    int i0 = blockIdx.x * 64;
    int tc = t & 31;
    int tr = t >> 5;
    int r0 = tr * 8;
    int c0 = tc * 4;                 // virtual col (0-63 impact, 64-127 timing)

    float acc[8][4];
#pragma unroll
    for (int i = 0; i < 8; ++i)
#pragma unroll
        for (int j = 0; j < 4; ++j) acc[i][j] = 0.f;

    for (int k0 = 0; k0 < 128; k0 += 32) {
        __syncthreads();
#pragma unroll
        for (int q = 0; q < 2; ++q) {
            int idx = t + q * 256;
            int r = idx >> 3, kq = idx & 7;
            float4 v4 = make_float4(0.f, 0.f, 0.f, 0.f);
            if (i0 + r < M) v4 = *(const float4*)&A[(size_t)(i0 + r) * 128 + k0 + kq * 4];
            *(float4*)&As[r * 32 + kq * 4] = v4;
        }
#pragma unroll
        for (int q = 0; q < 4; ++q) {
            int idx = (t + q * 256) * 4;       // flat into [32][128]
            int k = idx >> 7, cl = idx & 127;
            float4 v4 = (cl < 64)
                ? *(const float4*)&iw1[(size_t)(k0 + k) * 64 + cl]
                : *(const float4*)&tw1[(size_t)(k0 + k) * 64 + (cl - 64)];
            *(float4*)&Bs[idx] = v4;
        }
        __syncthreads();
#pragma unroll 8
        for (int k = 0; k < 32; k += 4) {
            float4 a4[8];
#pragma unroll
            for (int i = 0; i < 8; ++i)
                a4[i] = *(const float4*)&As[(r0 + i) * 32 + k];
            float4 b4[4];
#pragma unroll
            for (int kk = 0; kk < 4; ++kk)
                b4[kk] = *(const float4*)&Bs[(k + kk) * 128 + c0];
#pragma unroll
            for (int i = 0; i < 8; ++i) {
                const float* av = (const float*)&a4[i];
#pragma unroll
                for (int kk = 0; kk < 4; ++kk) {
                    acc[i][0] += av[kk] * b4[kk].x;
                    acc[i][1] += av[kk] * b4[kk].y;
                    acc[i][2] += av[kk] * b4[kk].z;
                    acc[i][3] += av[kk] * b4[kk].w;
                }
            }
        }
    }

    bool isimp = (tc < 16);
    int lc = isimp ? c0 : (c0 - 64);
    float v[8][4];
#pragma unroll
    for (int i = 0; i < 8; ++i)
#pragma unroll
        for (int j = 0; j < 4; ++j) {
            float b = isimp ? ib1[lc + j] : tb1[lc + j];
            float x = acc[i][j] + b;
            v[i][j] = x > 0.f ? x : 0.f;
        }
#pragma unroll
    for (int i = 0; i < 8; ++i) {
        int row = i0 + r0 + i;
        if (isimp) {
#pragma unroll
            for (int c = 0; c < 3; ++c) {
                float pc = v[i][0] * iw2[(lc + 0) * 3 + c] + v[i][1] * iw2[(lc + 1) * 3 + c]
                         + v[i][2] * iw2[(lc + 2) * 3 + c] + v[i][3] * iw2[(lc + 3) * 3 + c];
#pragma unroll
                for (int off = 8; off >= 1; off >>= 1) pc += __shfl_xor(pc, off);
                if (tc == 0 && row < M) out[(size_t)row * 3 + c] = pc + ib2[c];
            }
        } else {
#pragma unroll
            for (int d = 0; d < 2; ++d) {
                float pd = v[i][0] * tw2[(lc + 0) * 2 + d] + v[i][1] * tw2[(lc + 1) * 2 + d]
                         + v[i][2] * tw2[(lc + 2) * 2 + d] + v[i][3] * tw2[(lc + 3) * 2 + d];
#pragma unroll
                for (int off = 8; off >= 1; off >>= 1) pd += __shfl_xor(pd, off);
                if (tc == 16 && row < M) {
                    float a = pd + tb2[d];
                    float sp = a > 20.f ? a : log1pf(__expf(a));
                    out[(size_t)(NN * 3) + (size_t)row * 2 + d] = sp;
                }
            }
        }
    }
}

// ---------------- gat v14 == v10 exactly (measured 66 us, VALUBusy 62%):
// 2 nodes/wave, 32 lanes/node, uint2 gathers, 8-deep MLP, scalar es/ed, in-loop exp.
__global__ __launch_bounds__(256, 6) void gat_kernel(const unsigned* __restrict__ xpk,
                                                     const float* __restrict__ es,
                                                     const float* __restrict__ ed,
                                                     const int* __restrict__ rowptr,
                                                     const int* __restrict__ colidx,
                                                     float* __restrict__ h,   // in-out (residual)
                                                     const float* __restrict__ bc,
                                                     const float* __restrict__ g,
                                                     const float* __restrict__ be) {
    int wv = threadIdx.x >> 6, l = threadIdx.x & 63;
    int hf = l >> 5;                        // which node of the pair
    int lh = l & 31;
    int hd = lh >> 3;                       // head 0..3
    int j  = lh & 7;                        // 0..7
    int v = blockIdx.x * 8 + wv * 2 + hf;   // grid covers NN exactly (6250*8=50000)
    if (v >= NN) return;                    // defensive
    int s0 = rowptr[v], s1 = rowptr[v + 1];
    int len = s1 - s0;                      // >= 1 (self-loop)
    int nmax = max(len, __shfl_xor(len, 32));
    int c0 = (hd << 5) + (j << 2);          // 4 channels owned by this lane
    int xsel = (hd << 4) + (j << 1);        // even dword index into 64-dword xpk row
    float edv = ed[((unsigned)v << 2) + hd];

    // hoisted: residual row load overlaps the whole gather loop
    float4 h4 = *(const float4*)&h[(size_t)v * 128 + c0];

    float a0 = 0.f, a1 = 0.f, a2 = 0.f, a3 = 0.f, den = 0.f;
    for (int p8 = 0; p8 < nmax; p8 += 8) {
        int u[8];
#pragma unroll
        for (int q = 0; q < 8; ++q) {
            int idx = p8 + q;
            u[q] = colidx[s0 + (idx < len ? idx : len - 1)];   // clamp: always valid mem
        }
        uint2 xw[8];
#pragma unroll
        for (int q = 0; q < 8; ++q)
            xw[q] = *(const uint2*)&xpk[((unsigned)u[q] << 6) + xsel];
        float w[8];
#pragma unroll
        for (int q = 0; q < 8; ++q) {
            float e = es[((unsigned)u[q] << 2) + hd] + edv;
            e = fmaxf(e, 0.2f * e);         // leaky_relu, slope<1 => max form
            float ww = __expf(e);           // no max-shift: softmax shift-invariant
            w[q] = (p8 + q < len) ? ww : 0.f;
            den += w[q];
        }
#pragma unroll
        for (int q = 0; q < 8; ++q) {
            float2 x0 = unpack_bf16(xw[q].x);
            float2 x1 = unpack_bf16(xw[q].y);
            a0 = fmaf(w[q], x0.x, a0);
            a1 = fmaf(w[q], x0.y, a1);
            a2 = fmaf(w[q], x1.x, a2);
            a3 = fmaf(w[q], x1.y, a3);
        }
    }
    float rd = 1.f / den;

    // ---- epilogue: residual + LN + relu; reductions within the 32-lane half.
    float4 bc4 = *(const float4*)&bc[c0];
    float y0 = a0 * rd + bc4.x + h4.x;
    float y1 = a1 * rd + bc4.y + h4.y;
    float y2 = a2 * rd + bc4.z + h4.z;
    float y3 = a3 * rd + bc4.w + h4.w;

    float s = y0 + y1 + y2 + y3;
#pragma unroll
    for (int off = 16; off >= 1; off >>= 1) s += __shfl_xor(s, off);
    float mean = s * (1.f / 128.f);
    float d0 = y0 - mean, d1 = y1 - mean, d2 = y2 - mean, d3 = y3 - mean;
    float vv = d0 * d0 + d1 * d1 + d2 * d2 + d3 * d3;
#pragma unroll
    for (int off = 16; off >= 1; off >>= 1) vv += __shfl_xor(vv, off);
    float rstd = rsqrtf(vv * (1.f / 128.f) + 1e-5f);
    float4 g4  = *(const float4*)&g[c0];
    float4 be4 = *(const float4*)&be[c0];
    float z0 = d0 * rstd * g4.x + be4.x;
    float z1 = d1 * rstd * g4.y + be4.y;
    float z2 = d2 * rstd * g4.z + be4.z;
    float z3 = d3 * rstd * g4.w + be4.w;
    float4 o;
    o.x = z0 > 0.f ? z0 : 0.f;
    o.y = z1 > 0.f ? z1 : 0.f;
    o.z = z2 > 0.f ? z2 : 0.f;
    o.w = z3 > 0.f ? z3 : 0.f;
    *(float4*)&h[(size_t)v * 128 + c0] = o;   // all 64 lanes write (2 rows per wave)
}

extern "C" void kernel_launch(void* const* d_in, const int* in_sizes, int n_in,
                              void* d_out, int out_size, void* d_ws, size_t ws_size,
                              hipStream_t stream) {
    const float* x      = (const float*)d_in[0];
    const int*   ei     = (const int*)d_in[1];
    const float* enc_w1 = (const float*)d_in[2];
    const float* enc_b1 = (const float*)d_in[3];
    const float* enc_w2 = (const float*)d_in[4];
    const float* enc_b2 = (const float*)d_in[5];
    const float *W[3], *as_[3], *ad_[3], *bc[3], *g[3], *be[3];
    for (int l = 0; l < 3; ++l) {
        W[l]   = (const float*)d_in[6 + l * 6 + 0];
        as_[l] = (const float*)d_in[6 + l * 6 + 1];
        ad_[l] = (const float*)d_in[6 + l * 6 + 2];
        bc[l]  = (const float*)d_in[6 + l * 6 + 3];
        g[l]   = (const float*)d_in[6 + l * 6 + 4];
        be[l]  = (const float*)d_in[6 + l * 6 + 5];
    }
    const float* imp_w1 = (const float*)d_in[24];
    const float* imp_b1 = (const float*)d_in[25];
    const float* imp_w2 = (const float*)d_in[26];
    const float* imp_b2 = (const float*)d_in[27];
    const float* tim_w1 = (const float*)d_in[28];
    const float* tim_b1 = (const float*)d_in[29];
    const float* tim_w2 = (const float*)d_in[30];
    const float* tim_b2 = (const float*)d_in[31];

    int* gcursor = (int*)d_ws;               // NPART
    int* rowptr  = gcursor + NPART + 64;     // NN+1
    int* colidx  = rowptr + NN + 1;          // ETOT (+8 slack)
    uintptr_t pb = (uintptr_t)(colidx + ETOT + 8);
    pb = (pb + 255) & ~(uintptr_t)255;
    unsigned* pbuf = (unsigned*)pb;          // NPART*PCAP (7.3 MB)
    uintptr_t fb = (uintptr_t)(pbuf + (size_t)NPART * PCAP);
    fb = (fb + 255) & ~(uintptr_t)255;
    float* es = (float*)fb;                  // NN*4
    float* ed = es + (size_t)NN * 4;         // NN*4
    float* h  = ed + (size_t)NN * 4;         // NN*128 fp32
    float* xpf = h + (size_t)NN * 128;       // region sized NN*128 floats
    unsigned* xpk = (unsigned*)xpf;          // packed bf16 uses first half
    unsigned short* wtb = (unsigned short*)(xpf + (size_t)NN * 128); // 3 x 16384 bf16 (96 KB)
    float* tmp = xpf;                        // enc1 scratch aliases (dead before xpk lives)

    hipMemsetAsync(gcursor, 0, NPART * sizeof(int), stream);
    pass1_kernel<<<512, 256, 0, stream>>>(ei, gcursor, pbuf);
    pass2_kernel<<<NPART, 256, 0, stream>>>(pbuf, gcursor, rowptr, colidx);
    for (int l = 0; l < 3; ++l)
        wconv_kernel<<<64, 256, 0, stream>>>(W[l], wtb + (size_t)l * 16384);

    const int GB64 = (NN + 63) / 64;
    gemm_small_kernel<128, true><<<(NN + 31) / 32, 256, 0, stream>>>(x, enc_w1, enc_b1, tmp, NN, FINDIM);
    gemm128_kernel<<<GB64, 256, 0, stream>>>(tmp, enc_w2, enc_b2, h, NN);

    for (int l = 0; l < 3; ++l) {
        gemm_mfma_kernel<<<GB64, 256, 0, stream>>>(h, wtb + (size_t)l * 16384, xpk,
                                                   as_[l], ad_[l], es, ed, NN);
        gat_kernel<<<(NN + 7) / 8, 256, 0, stream>>>(xpk, es, ed, rowptr, colidx, h,
                                                     bc[l], g[l], be[l]);
    }

    gemm_heads_kernel<<<GB64, 256, 0, stream>>>(h, imp_w1, imp_b1, tim_w1, tim_b1,
                                                imp_w2, imp_b2, tim_w2, tim_b2,
                                                (float*)d_out, NN);
}

// Round 9
// 517.676 us; speedup vs baseline: 1.1482x; 1.0562x over previous
//
#include <hip/hip_runtime.h>
#include <hip/hip_bf16.h>
#include <math.h>

#define NN 50000
#define EDGES 1600000
#define ETOT (EDGES + NN)
#define FINDIM 39
#define NPART 256
#define PSZ 196        // dsts per partition; 256*196 = 50176 >= NN
#define PCAP 7100      // capacity per partition (avg 6468, +7.9 sigma)
#define P1TILE 4096

typedef __attribute__((ext_vector_type(8))) short short8;
typedef __attribute__((ext_vector_type(4))) float floatx4;

__device__ __forceinline__ unsigned pack_bf16(float a, float b) {
    __hip_bfloat162 t;
    t.x = __float2bfloat16(a);
    t.y = __float2bfloat16(b);
    return *(unsigned*)&t;
}
__device__ __forceinline__ float2 unpack_bf16(unsigned w) {
    float2 r;
    r.x = __uint_as_float(w << 16);
    r.y = __uint_as_float(w & 0xffff0000u);
    return r;
}

__device__ __forceinline__ int src_at(const int* ei, int i, bool i32) {
    return i32 ? ei[i] : ei[2 * i];
}
__device__ __forceinline__ int dst_at(const int* ei, int i, bool i32) {
    return i32 ? ei[EDGES + i] : ei[2 * (EDGES + i)];
}

// ---------------- CSR pass 1 (self-detecting int32/int64): bucket into 256 partitions ----------------
__global__ __launch_bounds__(256) void pass1_kernel(const int* __restrict__ ei,
                                                    int* __restrict__ gcursor,
                                                    unsigned* __restrict__ pbuf) {
    __shared__ unsigned raw[P1TILE];
    __shared__ unsigned srt[P1TILE];
    __shared__ int pcnt[NPART], poff[NPART], pcur[NPART], gb[NPART];
    __shared__ int i32flag;
    int t = threadIdx.x;
    if (t == 0) i32flag = 0;
    __syncthreads();
    int chunk = (ETOT + gridDim.x - 1) / gridDim.x;
    int c0 = blockIdx.x * chunk;
    int c1 = c0 + chunk; if (c1 > ETOT) c1 = ETOT;
    int sb = c0 < EDGES - 64 ? c0 : 0;
    if (t < 64 && ei[2 * (sb + t) + 1] != 0) i32flag = 1;
    __syncthreads();
    bool i32 = (i32flag != 0);
    for (int t0 = c0; t0 < c1; t0 += P1TILE) {
        int tn = c1 - t0; if (tn > P1TILE) tn = P1TILE;
        pcnt[t] = 0; pcur[t] = 0;
        __syncthreads();
        for (int i = t; i < tn; i += 256) {
            int e = t0 + i;
            int s, d;
            if (e < EDGES) { s = src_at(ei, e, i32); d = dst_at(ei, e, i32); }
            else { s = d = e - EDGES; }
            raw[i] = ((unsigned)s << 16) | (unsigned)d;
            atomicAdd(&pcnt[d / PSZ], 1);
        }
        __syncthreads();
        poff[t] = pcnt[t];
        __syncthreads();
        for (int off = 1; off < NPART; off <<= 1) {
            int v = (t >= off) ? poff[t - off] : 0;
            __syncthreads();
            poff[t] += v;
            __syncthreads();
        }
        poff[t] -= pcnt[t];                       // exclusive
        gb[t] = atomicAdd(&gcursor[t], pcnt[t]);  // global base for this tile's run
        __syncthreads();
        for (int i = t; i < tn; i += 256) {
            unsigned r = raw[i];
            int part = (int)(r & 0xFFFFu) / PSZ;
            int pos = poff[part] + atomicAdd(&pcur[part], 1);
            srt[pos] = r;
        }
        __syncthreads();
        for (int i = t; i < tn; i += 256) {
            unsigned r = srt[i];
            int part = (int)(r & 0xFFFFu) / PSZ;
            int gpos = gb[part] + (i - poff[part]);
            if (gpos < PCAP) pbuf[(size_t)part * PCAP + gpos] = r;
        }
        __syncthreads();
    }
}

// ---------------- CSR pass 2: per-partition exact sort -> rowptr + colidx (pbase inline) ----------------
__global__ __launch_bounds__(256) void pass2_kernel(const unsigned* __restrict__ pbuf,
                                                    const int* __restrict__ gcursor,
                                                    int* __restrict__ rowptr,
                                                    int* __restrict__ colidx) {
    __shared__ unsigned recs[PCAP];                 // 28.4 KB
    __shared__ int lhist[PSZ], lexcl[PSZ], lcur[PSZ];
    __shared__ int psm[NPART];
    int p = blockIdx.x;
    int t = threadIdx.x;
    // inline prefix over the 256 partition totals
    psm[t] = gcursor[t];
    __syncthreads();
    for (int off = 1; off < NPART; off <<= 1) {
        int x = (t >= off) ? psm[t - off] : 0;
        __syncthreads();
        psm[t] += x;
        __syncthreads();
    }
    int n = gcursor[p]; if (n > PCAP) n = PCAP;
    int base = psm[p] - gcursor[p];
    if (p == NPART - 1 && t == 0) rowptr[NN] = psm[NPART - 1];   // == ETOT
    int d0 = p * PSZ;
    int nd = NN - d0; if (nd > PSZ) nd = PSZ;
    if (nd < 0) nd = 0;
    for (int i = t; i < nd; i += 256) { lhist[i] = 0; lcur[i] = 0; }
    __syncthreads();
    for (int i = t; i < n; i += 256) {
        unsigned r = pbuf[(size_t)p * PCAP + i];
        recs[i] = r;
        atomicAdd(&lhist[(int)(r & 0xFFFFu) - d0], 1);
    }
    __syncthreads();
    for (int i = t; i < nd; i += 256) lexcl[i] = lhist[i];
    __syncthreads();
    for (int off = 1; off < PSZ; off <<= 1) {
        int a0 = 0;
        if (t < nd && t >= off) a0 = lexcl[t - off];
        __syncthreads();
        if (t < nd) lexcl[t] += a0;
        __syncthreads();
    }
    for (int i = t; i < nd; i += 256) {
        lexcl[i] -= lhist[i];                        // exclusive
        rowptr[d0 + i] = base + lexcl[i];
    }
    __syncthreads();
    for (int i = t; i < n; i += 256) {
        unsigned r = recs[i];
        int li = (int)(r & 0xFFFFu) - d0;
        int pos = base + lexcl[li] + atomicAdd(&lcur[li], 1);
        colidx[pos] = (int)(r >> 16);
    }
}

// ---------------- generic GEMM (K=39 encoder-1 only) ----------------
template <int NC, bool RELU>
__global__ __launch_bounds__(256) void gemm_small_kernel(const float* __restrict__ A,
                                                         const float* __restrict__ B,
                                                         const float* __restrict__ bias,
                                                         float* __restrict__ C, int M, int K) {
    constexpr int TM = 32;
    constexpr int GROUPS = 256 / NC;
    constexpr int RPG = TM / GROUPS;
    constexpr int KC = 64;
    __shared__ float As[TM * 128];
    __shared__ float Bs[KC * NC];
    int t = threadIdx.x;
    int i0 = blockIdx.x * TM;

    int rows = M - i0; if (rows > TM) rows = TM;
    for (int idx = t; idx < rows * K; idx += 256) {
        int r = idx / K, k = idx - r * K;
        As[r * K + k] = A[(size_t)(i0 + r) * K + k];
    }

    int col = t % NC, grp = t / NC;
    int rg0 = grp * RPG;
    float acc[RPG];
#pragma unroll
    for (int r = 0; r < RPG; ++r) acc[r] = 0.f;

    for (int k0 = 0; k0 < K; k0 += KC) {
        int kc = K - k0; if (kc > KC) kc = KC;
        __syncthreads();
        for (int idx = t; idx < kc * NC; idx += 256) Bs[idx] = B[(size_t)k0 * NC + idx];
        __syncthreads();
        for (int k = 0; k < kc; ++k) {
            float bv = Bs[k * NC + col];
#pragma unroll
            for (int r = 0; r < RPG; ++r) acc[r] += As[(rg0 + r) * K + k0 + k] * bv;
        }
    }

    float bb = bias ? bias[col] : 0.f;
#pragma unroll
    for (int r = 0; r < RPG; ++r) {
        int i = i0 + rg0 + r;
        if (i < M) {
            float v = acc[r] + bb;
            if (RELU) v = v > 0.f ? v : 0.f;
            C[(size_t)i * NC + col] = v;
        }
    }
}

// ---------------- weight prep: 5 matrices -> bf16 transposed wtb[m][c][k] ----------------
// m=0..2: W layers; m=3: enc_w2; m=4: [iw1|tw1] combined (c<64 impact, c>=64 timing).
__global__ __launch_bounds__(256) void wconv5_kernel(const float* __restrict__ W0,
                                                     const float* __restrict__ W1,
                                                     const float* __restrict__ W2,
                                                     const float* __restrict__ ew2,
                                                     const float* __restrict__ iw1,
                                                     const float* __restrict__ tw1,
                                                     unsigned short* __restrict__ wtb) {
    int idx = blockIdx.x * 256 + threadIdx.x;   // grid 320 -> 5*16384
    int m = idx >> 14;
    int r = idx & 16383;
    int c = r >> 7, k = r & 127;
    float v;
    if (m == 0) v = W0[(size_t)k * 128 + c];
    else if (m == 1) v = W1[(size_t)k * 128 + c];
    else if (m == 2) v = W2[(size_t)k * 128 + c];
    else if (m == 3) v = ew2[(size_t)k * 128 + c];
    else v = (c < 64) ? iw1[(size_t)k * 64 + c] : tw1[(size_t)k * 64 + (c - 64)];
    unsigned p = pack_bf16(v, 0.f);
    wtb[idx] = (unsigned short)(p & 0xffffu);
}

// ---------------- shared MFMA core: acc[n] = bf16(Arow) @ wtb, 16 rows x 128 cols per wave ----------------
__device__ __forceinline__ void mfma_core(const float* __restrict__ A, int arow, int valid,
                                          const unsigned short* __restrict__ wtb,
                                          int c, int grp, floatx4 acc[8]) {
#pragma unroll
    for (int n = 0; n < 8; ++n) acc[n] = (floatx4){0.f, 0.f, 0.f, 0.f};
    short8 af[4];
#pragma unroll
    for (int kc = 0; kc < 4; ++kc) {
        float4 f0 = make_float4(0.f, 0.f, 0.f, 0.f), f1 = f0;
        if (valid) {
            const float* hp = &A[(size_t)arow * 128 + (kc << 5) + (grp << 3)];
            f0 = *(const float4*)hp;
            f1 = *(const float4*)(hp + 4);
        }
        unsigned pk[4];
        pk[0] = pack_bf16(f0.x, f0.y);
        pk[1] = pack_bf16(f0.z, f0.w);
        pk[2] = pack_bf16(f1.x, f1.y);
        pk[3] = pack_bf16(f1.z, f1.w);
        af[kc] = *(short8*)pk;
    }
#pragma unroll
    for (int kc = 0; kc < 4; ++kc) {
#pragma unroll
        for (int n = 0; n < 8; ++n) {
            short8 bf = *(const short8*)&wtb[(size_t)(((n << 4) + c) * 128 + (kc << 5) + (grp << 3))];
            acc[n] = __builtin_amdgcn_mfma_f32_16x16x32_bf16(af[kc], bf, acc[n], 0, 0, 0);
        }
    }
}

// ---------------- MFMA GEMM (W layers): xp = bf16(h) @ W; epilogue xpk + es/ed ----------------
__global__ __launch_bounds__(256) void gemm_mfma_kernel(const float* __restrict__ H,
                                                        const unsigned short* __restrict__ wtb,
                                                        unsigned* __restrict__ XP,
                                                        const float* __restrict__ a_s,
                                                        const float* __restrict__ a_d,
                                                        float* __restrict__ es,
                                                        float* __restrict__ ed, int M) {
    int t = threadIdx.x;
    int w = t >> 6, l = t & 63;
    int c = l & 15, grp = l >> 4;
    int i0 = blockIdx.x * 64 + w * 16;
    int arow = i0 + c;

    floatx4 acc[8];
    mfma_core(H, arow, arow < M, wtb, c, grp, acc);

    float asv[8], adv[8];
#pragma unroll
    for (int n = 0; n < 8; ++n) { asv[n] = a_s[(n << 4) + c]; adv[n] = a_d[(n << 4) + c]; }

    float sp[4][4], dp[4][4];   // [r][head]
#pragma unroll
    for (int r = 0; r < 4; ++r)
#pragma unroll
        for (int hd = 0; hd < 4; ++hd) { sp[r][hd] = 0.f; dp[r][hd] = 0.f; }

#pragma unroll
    for (int n = 0; n < 8; ++n) {
#pragma unroll
        for (int r = 0; r < 4; ++r) {
            float vv = acc[n][r];
            float pv = __shfl_xor(vv, 1);
            int row = i0 + (grp << 2) + r;
            if (!(c & 1) && row < M)
                XP[(size_t)row * 64 + (n << 3) + (c >> 1)] = pack_bf16(vv, pv);
            sp[r][n >> 1] = fmaf(vv, asv[n], sp[r][n >> 1]);
            dp[r][n >> 1] = fmaf(vv, adv[n], dp[r][n >> 1]);
        }
    }
#pragma unroll
    for (int r = 0; r < 4; ++r)
#pragma unroll
        for (int hd = 0; hd < 4; ++hd) {
            float s = sp[r][hd], d = dp[r][hd];
#pragma unroll
            for (int off = 1; off <= 8; off <<= 1) {
                s += __shfl_xor(s, off);
                d += __shfl_xor(d, off);
            }
            sp[r][hd] = s; dp[r][hd] = d;
        }
    if (c < 4) {
#pragma unroll
        for (int r = 0; r < 4; ++r) {
            int row = i0 + (grp << 2) + r;
            if (row < M) {
                float s = (c == 0) ? sp[r][0] : (c == 1) ? sp[r][1] : (c == 2) ? sp[r][2] : sp[r][3];
                float d = (c == 0) ? dp[r][0] : (c == 1) ? dp[r][1] : (c == 2) ? dp[r][2] : dp[r][3];
                es[(size_t)row * 4 + c] = s;
                ed[(size_t)row * 4 + c] = d;
            }
        }
    }
}

// ---------------- MFMA GEMM (enc2): h = bf16(tmp) @ enc_w2 + b, fp32 out ----------------
__global__ __launch_bounds__(256) void gemm_mfma_bias_kernel(const float* __restrict__ A,
                                                             const unsigned short* __restrict__ wtb,
                                                             const float* __restrict__ bias,
                                                             float* __restrict__ C, int M) {
    int t = threadIdx.x;
    int w = t >> 6, l = t & 63;
    int c = l & 15, grp = l >> 4;
    int i0 = blockIdx.x * 64 + w * 16;
    int arow = i0 + c;

    floatx4 acc[8];
    mfma_core(A, arow, arow < M, wtb, c, grp, acc);

    float bv[8];
#pragma unroll
    for (int n = 0; n < 8; ++n) bv[n] = bias[(n << 4) + c];
#pragma unroll
    for (int n = 0; n < 8; ++n)
#pragma unroll
        for (int r = 0; r < 4; ++r) {
            int row = i0 + (grp << 2) + r;
            if (row < M) C[(size_t)row * 128 + (n << 4) + c] = acc[n][r] + bv[n];
        }
}

// ---------------- MFMA heads: layer1 via MFMA (128 virtual cols), layer2 in epilogue ----------------
__global__ __launch_bounds__(256) void gemm_mfma_heads_kernel(const float* __restrict__ H,
                                                              const unsigned short* __restrict__ wtb,
                                                              const float* __restrict__ ib1,
                                                              const float* __restrict__ tb1,
                                                              const float* __restrict__ iw2,
                                                              const float* __restrict__ ib2,
                                                              const float* __restrict__ tw2,
                                                              const float* __restrict__ tb2,
                                                              float* __restrict__ out, int M) {
    int t = threadIdx.x;
    int w = t >> 6, l = t & 63;
    int c = l & 15, grp = l >> 4;
    int i0 = blockIdx.x * 64 + w * 16;
    int arow = i0 + c;

    floatx4 acc[8];
    mfma_core(H, arow, arow < M, wtb, c, grp, acc);

    // layer-2 weights for this lane's columns: impact cols n*16+c (n<4), timing (n-4)*16+c
    float iw2v[4][3], tw2v[4][2], ib1v[4], tb1v[4];
#pragma unroll
    for (int n = 0; n < 4; ++n) {
        int lc = (n << 4) + c;
        ib1v[n] = ib1[lc];
        tb1v[n] = tb1[lc];
#pragma unroll
        for (int o = 0; o < 3; ++o) iw2v[n][o] = iw2[lc * 3 + o];
#pragma unroll
        for (int d = 0; d < 2; ++d) tw2v[n][d] = tw2[lc * 2 + d];
    }

    float pi[4][3], pt[4][2];
#pragma unroll
    for (int r = 0; r < 4; ++r) {
#pragma unroll
        for (int o = 0; o < 3; ++o) pi[r][o] = 0.f;
#pragma unroll
        for (int d = 0; d < 2; ++d) pt[r][d] = 0.f;
    }
#pragma unroll
    for (int n = 0; n < 4; ++n)
#pragma unroll
        for (int r = 0; r < 4; ++r) {
            float vi = acc[n][r] + ib1v[n];     vi = vi > 0.f ? vi : 0.f;
            float vt = acc[n + 4][r] + tb1v[n]; vt = vt > 0.f ? vt : 0.f;
#pragma unroll
            for (int o = 0; o < 3; ++o) pi[r][o] = fmaf(vi, iw2v[n][o], pi[r][o]);
#pragma unroll
            for (int d = 0; d < 2; ++d) pt[r][d] = fmaf(vt, tw2v[n][d], pt[r][d]);
        }
    // reduce over the 16 lanes (c) of this row group
#pragma unroll
    for (int r = 0; r < 4; ++r) {
#pragma unroll
        for (int o = 0; o < 3; ++o) {
            float s = pi[r][o];
#pragma unroll
            for (int off = 1; off <= 8; off <<= 1) s += __shfl_xor(s, off);
            pi[r][o] = s;
        }
#pragma unroll
        for (int d = 0; d < 2; ++d) {
            float s = pt[r][d];
#pragma unroll
            for (int off = 1; off <= 8; off <<= 1) s += __shfl_xor(s, off);
            pt[r][d] = s;
        }
    }
    if (c == 0) {
#pragma unroll
        for (int r = 0; r < 4; ++r) {
            int row = i0 + (grp << 2) + r;
            if (row < M) {
#pragma unroll
                for (int o = 0; o < 3; ++o) out[(size_t)row * 3 + o] = pi[r][o] + ib2[o];
#pragma unroll
                for (int d = 0; d < 2; ++d) {
                    float a = pt[r][d] + tb2[d];
                    float sp = a > 20.f ? a : log1pf(__expf(a));
                    out[(size_t)(NN * 3) + (size_t)row * 2 + d] = sp;
                }
            }
        }
    }
}

// ---------------- gat (v10 form, twice-verified at 66 us / VALUBusy 62%):
// 2 nodes/wave, 32 lanes/node, uint2 gathers, 8-deep MLP, scalar es/ed, in-loop exp.
__global__ __launch_bounds__(256, 6) void gat_kernel(const unsigned* __restrict__ xpk,
                                                     const float* __restrict__ es,
                                                     const float* __restrict__ ed,
                                                     const int* __restrict__ rowptr,
                                                     const int* __restrict__ colidx,
                                                     float* __restrict__ h,   // in-out (residual)
                                                     const float* __restrict__ bc,
                                                     const float* __restrict__ g,
                                                     const float* __restrict__ be) {
    int wv = threadIdx.x >> 6, l = threadIdx.x & 63;
    int hf = l >> 5;                        // which node of the pair
    int lh = l & 31;
    int hd = lh >> 3;                       // head 0..3
    int j  = lh & 7;                        // 0..7
    int v = blockIdx.x * 8 + wv * 2 + hf;   // grid covers NN exactly (6250*8=50000)
    if (v >= NN) return;                    // defensive
    int s0 = rowptr[v], s1 = rowptr[v + 1];
    int len = s1 - s0;                      // >= 1 (self-loop)
    int nmax = max(len, __shfl_xor(len, 32));
    int c0 = (hd << 5) + (j << 2);          // 4 channels owned by this lane
    int xsel = (hd << 4) + (j << 1);        // even dword index into 64-dword xpk row
    float edv = ed[((unsigned)v << 2) + hd];

    // hoisted: residual row load overlaps the whole gather loop
    float4 h4 = *(const float4*)&h[(size_t)v * 128 + c0];

    float a0 = 0.f, a1 = 0.f, a2 = 0.f, a3 = 0.f, den = 0.f;
    for (int p8 = 0; p8 < nmax; p8 += 8) {
        int u[8];
#pragma unroll
        for (int q = 0; q < 8; ++q) {
            int idx = p8 + q;
            u[q] = colidx[s0 + (idx < len ? idx : len - 1)];   // clamp: always valid mem
        }
        uint2 xw[8];
#pragma unroll
        for (int q = 0; q < 8; ++q)
            xw[q] = *(const uint2*)&xpk[((unsigned)u[q] << 6) + xsel];
        float w[8];
#pragma unroll
        for (int q = 0; q < 8; ++q) {
            float e = es[((unsigned)u[q] << 2) + hd] + edv;
            e = fmaxf(e, 0.2f * e);         // leaky_relu, slope<1 => max form
            float ww = __expf(e);           // no max-shift: softmax shift-invariant
            w[q] = (p8 + q < len) ? ww : 0.f;
            den += w[q];
        }
#pragma unroll
        for (int q = 0; q < 8; ++q) {
            float2 x0 = unpack_bf16(xw[q].x);
            float2 x1 = unpack_bf16(xw[q].y);
            a0 = fmaf(w[q], x0.x, a0);
            a1 = fmaf(w[q], x0.y, a1);
            a2 = fmaf(w[q], x1.x, a2);
            a3 = fmaf(w[q], x1.y, a3);
        }
    }
    float rd = 1.f / den;

    // ---- epilogue: residual + LN + relu; reductions within the 32-lane half.
    float4 bc4 = *(const float4*)&bc[c0];
    float y0 = a0 * rd + bc4.x + h4.x;
    float y1 = a1 * rd + bc4.y + h4.y;
    float y2 = a2 * rd + bc4.z + h4.z;
    float y3 = a3 * rd + bc4.w + h4.w;

    float s = y0 + y1 + y2 + y3;
#pragma unroll
    for (int off = 16; off >= 1; off >>= 1) s += __shfl_xor(s, off);
    float mean = s * (1.f / 128.f);
    float d0 = y0 - mean, d1 = y1 - mean, d2 = y2 - mean, d3 = y3 - mean;
    float vv = d0 * d0 + d1 * d1 + d2 * d2 + d3 * d3;
#pragma unroll
    for (int off = 16; off >= 1; off >>= 1) vv += __shfl_xor(vv, off);
    float rstd = rsqrtf(vv * (1.f / 128.f) + 1e-5f);
    float4 g4  = *(const float4*)&g[c0];
    float4 be4 = *(const float4*)&be[c0];
    float z0 = d0 * rstd * g4.x + be4.x;
    float z1 = d1 * rstd * g4.y + be4.y;
    float z2 = d2 * rstd * g4.z + be4.z;
    float z3 = d3 * rstd * g4.w + be4.w;
    float4 o;
    o.x = z0 > 0.f ? z0 : 0.f;
    o.y = z1 > 0.f ? z1 : 0.f;
    o.z = z2 > 0.f ? z2 : 0.f;
    o.w = z3 > 0.f ? z3 : 0.f;
    *(float4*)&h[(size_t)v * 128 + c0] = o;   // all 64 lanes write (2 rows per wave)
}

extern "C" void kernel_launch(void* const* d_in, const int* in_sizes, int n_in,
                              void* d_out, int out_size, void* d_ws, size_t ws_size,
                              hipStream_t stream) {
    const float* x      = (const float*)d_in[0];
    const int*   ei     = (const int*)d_in[1];
    const float* enc_w1 = (const float*)d_in[2];
    const float* enc_b1 = (const float*)d_in[3];
    const float* enc_w2 = (const float*)d_in[4];
    const float* enc_b2 = (const float*)d_in[5];
    const float *W[3], *as_[3], *ad_[3], *bc[3], *g[3], *be[3];
    for (int l = 0; l < 3; ++l) {
        W[l]   = (const float*)d_in[6 + l * 6 + 0];
        as_[l] = (const float*)d_in[6 + l * 6 + 1];
        ad_[l] = (const float*)d_in[6 + l * 6 + 2];
        bc[l]  = (const float*)d_in[6 + l * 6 + 3];
        g[l]   = (const float*)d_in[6 + l * 6 + 4];
        be[l]  = (const float*)d_in[6 + l * 6 + 5];
    }
    const float* imp_w1 = (const float*)d_in[24];
    const float* imp_b1 = (const float*)d_in[25];
    const float* imp_w2 = (const float*)d_in[26];
    const float* imp_b2 = (const float*)d_in[27];
    const float* tim_w1 = (const float*)d_in[28];
    const float* tim_b1 = (const float*)d_in[29];
    const float* tim_w2 = (const float*)d_in[30];
    const float* tim_b2 = (const float*)d_in[31];

    int* gcursor = (int*)d_ws;               // NPART
    int* rowptr  = gcursor + NPART + 64;     // NN+1
    int* colidx  = rowptr + NN + 1;          // ETOT (+8 slack)
    uintptr_t pb = (uintptr_t)(colidx + ETOT + 8);
    pb = (pb + 255) & ~(uintptr_t)255;
    unsigned* pbuf = (unsigned*)pb;          // NPART*PCAP (7.3 MB)
    uintptr_t fb = (uintptr_t)(pbuf + (size_t)NPART * PCAP);
    fb = (fb + 255) & ~(uintptr_t)255;
    float* es = (float*)fb;                  // NN*4
    float* ed = es + (size_t)NN * 4;         // NN*4
    float* h  = ed + (size_t)NN * 4;         // NN*128 fp32
    float* xpf = h + (size_t)NN * 128;       // region sized NN*128 floats
    unsigned* xpk = (unsigned*)xpf;          // packed bf16 uses first half
    unsigned short* wtb = (unsigned short*)(xpf + (size_t)NN * 128); // 5 x 16384 bf16 (160 KB)
    float* tmp = xpf;                        // enc1 scratch aliases (dead before xpk lives)

    hipMemsetAsync(gcursor, 0, NPART * sizeof(int), stream);
    pass1_kernel<<<512, 256, 0, stream>>>(ei, gcursor, pbuf);
    pass2_kernel<<<NPART, 256, 0, stream>>>(pbuf, gcursor, rowptr, colidx);
    wconv5_kernel<<<320, 256, 0, stream>>>(W[0], W[1], W[2], enc_w2, imp_w1, tim_w1, wtb);

    const int GB64 = (NN + 63) / 64;
    gemm_small_kernel<128, true><<<(NN + 31) / 32, 256, 0, stream>>>(x, enc_w1, enc_b1, tmp, NN, FINDIM);
    gemm_mfma_bias_kernel<<<GB64, 256, 0, stream>>>(tmp, wtb + (size_t)3 * 16384, enc_b2, h, NN);

    for (int l = 0; l < 3; ++l) {
        gemm_mfma_kernel<<<GB64, 256, 0, stream>>>(h, wtb + (size_t)l * 16384, xpk,
                                                   as_[l], ad_[l], es, ed, NN);
        gat_kernel<<<(NN + 7) / 8, 256, 0, stream>>>(xpk, es, ed, rowptr, colidx, h,
                                                     bc[l], g[l], be[l]);
    }

    gemm_mfma_heads_kernel<<<GB64, 256, 0, stream>>>(h, wtb + (size_t)4 * 16384,
                                                     imp_b1, tim_b1, imp_w2, imp_b2,
                                                     tim_w2, tim_b2, (float*)d_out, NN);
}

// Round 10
// 510.809 us; speedup vs baseline: 1.1637x; 1.0134x over previous
//
#include <hip/hip_runtime.h>
#include <hip/hip_bf16.h>
#include <math.h>

#define NN 50000
#define EDGES 1600000
#define ETOT (EDGES + NN)
#define FINDIM 39
#define NPART 256
#define PSZ 196        // dsts per partition; 256*196 = 50176 >= NN
#define PCAP 7100      // capacity per partition (avg 6468, +7.9 sigma)
#define P1TILE 4096

typedef __attribute__((ext_vector_type(8))) short short8;
typedef __attribute__((ext_vector_type(4))) float floatx4;

__device__ __forceinline__ unsigned pack_bf16(float a, float b) {
    __hip_bfloat162 t;
    t.x = __float2bfloat16(a);
    t.y = __float2bfloat16(b);
    return *(unsigned*)&t;
}
__device__ __forceinline__ float2 unpack_bf16(unsigned w) {
    float2 r;
    r.x = __uint_as_float(w << 16);
    r.y = __uint_as_float(w & 0xffff0000u);
    return r;
}

__device__ __forceinline__ int src_at(const int* ei, int i, bool i32) {
    return i32 ? ei[i] : ei[2 * i];
}
__device__ __forceinline__ int dst_at(const int* ei, int i, bool i32) {
    return i32 ? ei[EDGES + i] : ei[2 * (EDGES + i)];
}

// ---------------- CSR pass 1 (1024 threads: 16 waves/block for the atomic phases) ----------------
__global__ __launch_bounds__(1024) void pass1_kernel(const int* __restrict__ ei,
                                                     int* __restrict__ gcursor,
                                                     unsigned* __restrict__ pbuf) {
    __shared__ unsigned raw[P1TILE];
    __shared__ unsigned srt[P1TILE];
    __shared__ int pcnt[NPART], poff[NPART], pcur[NPART], gb[NPART];
    __shared__ int i32flag;
    int t = threadIdx.x;
    if (t == 0) i32flag = 0;
    __syncthreads();
    int chunk = (ETOT + gridDim.x - 1) / gridDim.x;
    int c0 = blockIdx.x * chunk;
    int c1 = c0 + chunk; if (c1 > ETOT) c1 = ETOT;
    int sb = c0 < EDGES - 64 ? c0 : 0;
    if (t < 64 && ei[2 * (sb + t) + 1] != 0) i32flag = 1;
    __syncthreads();
    bool i32 = (i32flag != 0);
    for (int t0 = c0; t0 < c1; t0 += P1TILE) {
        int tn = c1 - t0; if (tn > P1TILE) tn = P1TILE;
        if (t < NPART) { pcnt[t] = 0; pcur[t] = 0; }
        __syncthreads();
        for (int i = t; i < tn; i += 1024) {
            int e = t0 + i;
            int s, d;
            if (e < EDGES) { s = src_at(ei, e, i32); d = dst_at(ei, e, i32); }
            else { s = d = e - EDGES; }
            raw[i] = ((unsigned)s << 16) | (unsigned)d;
            atomicAdd(&pcnt[d / PSZ], 1);
        }
        __syncthreads();
        if (t < NPART) poff[t] = pcnt[t];
        __syncthreads();
        for (int off = 1; off < NPART; off <<= 1) {
            int v = (t < NPART && t >= off) ? poff[t - off] : 0;
            __syncthreads();
            if (t < NPART) poff[t] += v;
            __syncthreads();
        }
        if (t < NPART) {
            poff[t] -= pcnt[t];                       // exclusive
            gb[t] = atomicAdd(&gcursor[t], pcnt[t]);  // global base for this tile's run
        }
        __syncthreads();
        for (int i = t; i < tn; i += 1024) {
            unsigned r = raw[i];
            int part = (int)(r & 0xFFFFu) / PSZ;
            int pos = poff[part] + atomicAdd(&pcur[part], 1);
            srt[pos] = r;
        }
        __syncthreads();
        for (int i = t; i < tn; i += 1024) {
            unsigned r = srt[i];
            int part = (int)(r & 0xFFFFu) / PSZ;
            int gpos = gb[part] + (i - poff[part]);
            if (gpos < PCAP) pbuf[(size_t)part * PCAP + gpos] = r;
        }
        __syncthreads();
    }
}

// ---------------- CSR pass 2 (1024 threads: 16 waves/block, was 4) ----------------
__global__ __launch_bounds__(1024) void pass2_kernel(const unsigned* __restrict__ pbuf,
                                                     const int* __restrict__ gcursor,
                                                     int* __restrict__ rowptr,
                                                     int* __restrict__ colidx) {
    __shared__ unsigned recs[PCAP];                 // 28.4 KB
    __shared__ int lhist[PSZ], lexcl[PSZ], lcur[PSZ];
    __shared__ int psm[NPART];
    int p = blockIdx.x;
    int t = threadIdx.x;
    // inline prefix over the 256 partition totals
    if (t < NPART) psm[t] = gcursor[t];
    __syncthreads();
    for (int off = 1; off < NPART; off <<= 1) {
        int x = (t < NPART && t >= off) ? psm[t - off] : 0;
        __syncthreads();
        if (t < NPART) psm[t] += x;
        __syncthreads();
    }
    int n = gcursor[p]; if (n > PCAP) n = PCAP;
    int base = psm[p] - gcursor[p];
    if (p == NPART - 1 && t == 0) rowptr[NN] = psm[NPART - 1];   // == ETOT
    int d0 = p * PSZ;
    int nd = NN - d0; if (nd > PSZ) nd = PSZ;
    if (nd < 0) nd = 0;
    for (int i = t; i < nd; i += 1024) { lhist[i] = 0; lcur[i] = 0; }
    __syncthreads();
    for (int i = t; i < n; i += 1024) {
        unsigned r = pbuf[(size_t)p * PCAP + i];
        recs[i] = r;
        atomicAdd(&lhist[(int)(r & 0xFFFFu) - d0], 1);
    }
    __syncthreads();
    for (int i = t; i < nd; i += 1024) lexcl[i] = lhist[i];
    __syncthreads();
    for (int off = 1; off < PSZ; off <<= 1) {
        int a0 = 0;
        if (t < nd && t >= off) a0 = lexcl[t - off];
        __syncthreads();
        if (t < nd) lexcl[t] += a0;
        __syncthreads();
    }
    for (int i = t; i < nd; i += 1024) {
        lexcl[i] -= lhist[i];                        // exclusive
        rowptr[d0 + i] = base + lexcl[i];
    }
    __syncthreads();
    for (int i = t; i < n; i += 1024) {
        unsigned r = recs[i];
        int li = (int)(r & 0xFFFFu) - d0;
        int pos = base + lexcl[li] + atomicAdd(&lcur[li], 1);
        colidx[pos] = (int)(r >> 16);
    }
}

// ---------------- generic GEMM (K=39 encoder-1 only; K compile-time -> no int div) ----------------
template <int NC, bool RELU, int K>
__global__ __launch_bounds__(256) void gemm_small_kernel(const float* __restrict__ A,
                                                         const float* __restrict__ B,
                                                         const float* __restrict__ bias,
                                                         float* __restrict__ C, int M) {
    constexpr int TM = 32;
    constexpr int GROUPS = 256 / NC;
    constexpr int RPG = TM / GROUPS;
    constexpr int KC = 64;
    __shared__ float As[TM * 128];
    __shared__ float Bs[KC * NC];
    int t = threadIdx.x;
    int i0 = blockIdx.x * TM;

    int rows = M - i0; if (rows > TM) rows = TM;
    for (int idx = t; idx < rows * K; idx += 256) {
        int r = idx / K, k = idx - r * K;
        As[r * K + k] = A[(size_t)(i0 + r) * K + k];
    }

    int col = t % NC, grp = t / NC;
    int rg0 = grp * RPG;
    float acc[RPG];
#pragma unroll
    for (int r = 0; r < RPG; ++r) acc[r] = 0.f;

    for (int k0 = 0; k0 < K; k0 += KC) {
        int kc = K - k0; if (kc > KC) kc = KC;
        __syncthreads();
        for (int idx = t; idx < kc * NC; idx += 256) Bs[idx] = B[(size_t)k0 * NC + idx];
        __syncthreads();
        for (int k = 0; k < kc; ++k) {
            float bv = Bs[k * NC + col];
#pragma unroll
            for (int r = 0; r < RPG; ++r) acc[r] += As[(rg0 + r) * K + k0 + k] * bv;
        }
    }

    float bb = bias ? bias[col] : 0.f;
#pragma unroll
    for (int r = 0; r < RPG; ++r) {
        int i = i0 + rg0 + r;
        if (i < M) {
            float v = acc[r] + bb;
            if (RELU) v = v > 0.f ? v : 0.f;
            C[(size_t)i * NC + col] = v;
        }
    }
}

// ---------------- weight prep: 5 matrices -> bf16 transposed wtb[m][c][k]; also zeroes gcursor ----------------
// m=0..2: W layers; m=3: enc_w2; m=4: [iw1|tw1] combined (c<64 impact, c>=64 timing).
__global__ __launch_bounds__(256) void wconv5_kernel(const float* __restrict__ W0,
                                                     const float* __restrict__ W1,
                                                     const float* __restrict__ W2,
                                                     const float* __restrict__ ew2,
                                                     const float* __restrict__ iw1,
                                                     const float* __restrict__ tw1,
                                                     unsigned short* __restrict__ wtb,
                                                     int* __restrict__ gcursor) {
    if (blockIdx.x == 0 && threadIdx.x < NPART) gcursor[threadIdx.x] = 0;
    int idx = blockIdx.x * 256 + threadIdx.x;   // grid 320 -> 5*16384
    int m = idx >> 14;
    int r = idx & 16383;
    int c = r >> 7, k = r & 127;
    float v;
    if (m == 0) v = W0[(size_t)k * 128 + c];
    else if (m == 1) v = W1[(size_t)k * 128 + c];
    else if (m == 2) v = W2[(size_t)k * 128 + c];
    else if (m == 3) v = ew2[(size_t)k * 128 + c];
    else v = (c < 64) ? iw1[(size_t)k * 64 + c] : tw1[(size_t)k * 64 + (c - 64)];
    unsigned p = pack_bf16(v, 0.f);
    wtb[idx] = (unsigned short)(p & 0xffffu);
}

// ---------------- shared MFMA core: acc[n] = bf16(Arow) @ wtb, 16 rows x 128 cols per wave ----------------
__device__ __forceinline__ void mfma_core(const float* __restrict__ A, int arow, int valid,
                                          const unsigned short* __restrict__ wtb,
                                          int c, int grp, floatx4 acc[8]) {
#pragma unroll
    for (int n = 0; n < 8; ++n) acc[n] = (floatx4){0.f, 0.f, 0.f, 0.f};
    short8 af[4];
#pragma unroll
    for (int kc = 0; kc < 4; ++kc) {
        float4 f0 = make_float4(0.f, 0.f, 0.f, 0.f), f1 = f0;
        if (valid) {
            const float* hp = &A[(size_t)arow * 128 + (kc << 5) + (grp << 3)];
            f0 = *(const float4*)hp;
            f1 = *(const float4*)(hp + 4);
        }
        unsigned pk[4];
        pk[0] = pack_bf16(f0.x, f0.y);
        pk[1] = pack_bf16(f0.z, f0.w);
        pk[2] = pack_bf16(f1.x, f1.y);
        pk[3] = pack_bf16(f1.z, f1.w);
        af[kc] = *(short8*)pk;
    }
#pragma unroll
    for (int kc = 0; kc < 4; ++kc) {
#pragma unroll
        for (int n = 0; n < 8; ++n) {
            short8 bf = *(const short8*)&wtb[(size_t)(((n << 4) + c) * 128 + (kc << 5) + (grp << 3))];
            acc[n] = __builtin_amdgcn_mfma_f32_16x16x32_bf16(af[kc], bf, acc[n], 0, 0, 0);
        }
    }
}

// ---------------- MFMA GEMM (W layers): xp = bf16(h) @ W; epilogue xpk + es/ed ----------------
__global__ __launch_bounds__(256) void gemm_mfma_kernel(const float* __restrict__ H,
                                                        const unsigned short* __restrict__ wtb,
                                                        unsigned* __restrict__ XP,
                                                        const float* __restrict__ a_s,
                                                        const float* __restrict__ a_d,
                                                        float* __restrict__ es,
                                                        float* __restrict__ ed, int M) {
    int t = threadIdx.x;
    int w = t >> 6, l = t & 63;
    int c = l & 15, grp = l >> 4;
    int i0 = blockIdx.x * 64 + w * 16;
    int arow = i0 + c;

    floatx4 acc[8];
    mfma_core(H, arow, arow < M, wtb, c, grp, acc);

    float asv[8], adv[8];
#pragma unroll
    for (int n = 0; n < 8; ++n) { asv[n] = a_s[(n << 4) + c]; adv[n] = a_d[(n << 4) + c]; }

    float sp[4][4], dp[4][4];   // [r][head]
#pragma unroll
    for (int r = 0; r < 4; ++r)
#pragma unroll
        for (int hd = 0; hd < 4; ++hd) { sp[r][hd] = 0.f; dp[r][hd] = 0.f; }

#pragma unroll
    for (int n = 0; n < 8; ++n) {
#pragma unroll
        for (int r = 0; r < 4; ++r) {
            float vv = acc[n][r];
            float pv = __shfl_xor(vv, 1);
            int row = i0 + (grp << 2) + r;
            if (!(c & 1) && row < M)
                XP[(size_t)row * 64 + (n << 3) + (c >> 1)] = pack_bf16(vv, pv);
            sp[r][n >> 1] = fmaf(vv, asv[n], sp[r][n >> 1]);
            dp[r][n >> 1] = fmaf(vv, adv[n], dp[r][n >> 1]);
        }
    }
#pragma unroll
    for (int r = 0; r < 4; ++r)
#pragma unroll
        for (int hd = 0; hd < 4; ++hd) {
            float s = sp[r][hd], d = dp[r][hd];
#pragma unroll
            for (int off = 1; off <= 8; off <<= 1) {
                s += __shfl_xor(s, off);
                d += __shfl_xor(d, off);
            }
            sp[r][hd] = s; dp[r][hd] = d;
        }
    if (c < 4) {
#pragma unroll
        for (int r = 0; r < 4; ++r) {
            int row = i0 + (grp << 2) + r;
            if (row < M) {
                float s = (c == 0) ? sp[r][0] : (c == 1) ? sp[r][1] : (c == 2) ? sp[r][2] : sp[r][3];
                float d = (c == 0) ? dp[r][0] : (c == 1) ? dp[r][1] : (c == 2) ? dp[r][2] : dp[r][3];
                es[(size_t)row * 4 + c] = s;
                ed[(size_t)row * 4 + c] = d;
            }
        }
    }
}

// ---------------- MFMA GEMM (enc2): h = bf16(tmp) @ enc_w2 + b, fp32 out ----------------
__global__ __launch_bounds__(256) void gemm_mfma_bias_kernel(const float* __restrict__ A,
                                                             const unsigned short* __restrict__ wtb,
                                                             const float* __restrict__ bias,
                                                             float* __restrict__ C, int M) {
    int t = threadIdx.x;
    int w = t >> 6, l = t & 63;
    int c = l & 15, grp = l >> 4;
    int i0 = blockIdx.x * 64 + w * 16;
    int arow = i0 + c;

    floatx4 acc[8];
    mfma_core(A, arow, arow < M, wtb, c, grp, acc);

    float bv[8];
#pragma unroll
    for (int n = 0; n < 8; ++n) bv[n] = bias[(n << 4) + c];
#pragma unroll
    for (int n = 0; n < 8; ++n)
#pragma unroll
        for (int r = 0; r < 4; ++r) {
            int row = i0 + (grp << 2) + r;
            if (row < M) C[(size_t)row * 128 + (n << 4) + c] = acc[n][r] + bv[n];
        }
}

// ---------------- MFMA heads: layer1 via MFMA (128 virtual cols), layer2 in epilogue ----------------
__global__ __launch_bounds__(256) void gemm_mfma_heads_kernel(const float* __restrict__ H,
                                                              const unsigned short* __restrict__ wtb,
                                                              const float* __restrict__ ib1,
                                                              const float* __restrict__ tb1,
                                                              const float* __restrict__ iw2,
                                                              const float* __restrict__ ib2,
                                                              const float* __restrict__ tw2,
                                                              const float* __restrict__ tb2,
                                                              float* __restrict__ out, int M) {
    int t = threadIdx.x;
    int w = t >> 6, l = t & 63;
    int c = l & 15, grp = l >> 4;
    int i0 = blockIdx.x * 64 + w * 16;
    int arow = i0 + c;

    floatx4 acc[8];
    mfma_core(H, arow, arow < M, wtb, c, grp, acc);

    // layer-2 weights for this lane's columns: impact cols n*16+c (n<4), timing (n-4)*16+c
    float iw2v[4][3], tw2v[4][2], ib1v[4], tb1v[4];
#pragma unroll
    for (int n = 0; n < 4; ++n) {
        int lc = (n << 4) + c;
        ib1v[n] = ib1[lc];
        tb1v[n] = tb1[lc];
#pragma unroll
        for (int o = 0; o < 3; ++o) iw2v[n][o] = iw2[lc * 3 + o];
#pragma unroll
        for (int d = 0; d < 2; ++d) tw2v[n][d] = tw2[lc * 2 + d];
    }

    float pi[4][3], pt[4][2];
#pragma unroll
    for (int r = 0; r < 4; ++r) {
#pragma unroll
        for (int o = 0; o < 3; ++o) pi[r][o] = 0.f;
#pragma unroll
        for (int d = 0; d < 2; ++d) pt[r][d] = 0.f;
    }
#pragma unroll
    for (int n = 0; n < 4; ++n)
#pragma unroll
        for (int r = 0; r < 4; ++r) {
            float vi = acc[n][r] + ib1v[n];     vi = vi > 0.f ? vi : 0.f;
            float vt = acc[n + 4][r] + tb1v[n]; vt = vt > 0.f ? vt : 0.f;
#pragma unroll
            for (int o = 0; o < 3; ++o) pi[r][o] = fmaf(vi, iw2v[n][o], pi[r][o]);
#pragma unroll
            for (int d = 0; d < 2; ++d) pt[r][d] = fmaf(vt, tw2v[n][d], pt[r][d]);
        }
    // reduce over the 16 lanes (c) of this row group
#pragma unroll
    for (int r = 0; r < 4; ++r) {
#pragma unroll
        for (int o = 0; o < 3; ++o) {
            float s = pi[r][o];
#pragma unroll
            for (int off = 1; off <= 8; off <<= 1) s += __shfl_xor(s, off);
            pi[r][o] = s;
        }
#pragma unroll
        for (int d = 0; d < 2; ++d) {
            float s = pt[r][d];
#pragma unroll
            for (int off = 1; off <= 8; off <<= 1) s += __shfl_xor(s, off);
            pt[r][d] = s;
        }
    }
    if (c == 0) {
#pragma unroll
        for (int r = 0; r < 4; ++r) {
            int row = i0 + (grp << 2) + r;
            if (row < M) {
#pragma unroll
                for (int o = 0; o < 3; ++o) out[(size_t)row * 3 + o] = pi[r][o] + ib2[o];
#pragma unroll
                for (int d = 0; d < 2; ++d) {
                    float a = pt[r][d] + tb2[d];
                    float sp = a > 20.f ? a : log1pf(__expf(a));
                    out[(size_t)(NN * 3) + (size_t)row * 2 + d] = sp;
                }
            }
        }
    }
}

// ---------------- gat (v10 form, twice-verified at 66 us / VALUBusy 62%):
// 2 nodes/wave, 32 lanes/node, uint2 gathers, 8-deep MLP, scalar es/ed, in-loop exp.
__global__ __launch_bounds__(256, 6) void gat_kernel(const unsigned* __restrict__ xpk,
                                                     const float* __restrict__ es,
                                                     const float* __restrict__ ed,
                                                     const int* __restrict__ rowptr,
                                                     const int* __restrict__ colidx,
                                                     float* __restrict__ h,   // in-out (residual)
                                                     const float* __restrict__ bc,
                                                     const float* __restrict__ g,
                                                     const float* __restrict__ be) {
    int wv = threadIdx.x >> 6, l = threadIdx.x & 63;
    int hf = l >> 5;                        // which node of the pair
    int lh = l & 31;
    int hd = lh >> 3;                       // head 0..3
    int j  = lh & 7;                        // 0..7
    int v = blockIdx.x * 8 + wv * 2 + hf;   // grid covers NN exactly (6250*8=50000)
    if (v >= NN) return;                    // defensive
    int s0 = rowptr[v], s1 = rowptr[v + 1];
    int len = s1 - s0;                      // >= 1 (self-loop)
    int nmax = max(len, __shfl_xor(len, 32));
    int c0 = (hd << 5) + (j << 2);          // 4 channels owned by this lane
    int xsel = (hd << 4) + (j << 1);        // even dword index into 64-dword xpk row
    float edv = ed[((unsigned)v << 2) + hd];

    // hoisted: residual row load overlaps the whole gather loop
    float4 h4 = *(const float4*)&h[(size_t)v * 128 + c0];

    float a0 = 0.f, a1 = 0.f, a2 = 0.f, a3 = 0.f, den = 0.f;
    for (int p8 = 0; p8 < nmax; p8 += 8) {
        int u[8];
#pragma unroll
        for (int q = 0; q < 8; ++q) {
            int idx = p8 + q;
            u[q] = colidx[s0 + (idx < len ? idx : len - 1)];   // clamp: always valid mem
        }
        uint2 xw[8];
#pragma unroll
        for (int q = 0; q < 8; ++q)
            xw[q] = *(const uint2*)&xpk[((unsigned)u[q] << 6) + xsel];
        float w[8];
#pragma unroll
        for (int q = 0; q < 8; ++q) {
            float e = es[((unsigned)u[q] << 2) + hd] + edv;
            e = fmaxf(e, 0.2f * e);         // leaky_relu, slope<1 => max form
            float ww = __expf(e);           // no max-shift: softmax shift-invariant
            w[q] = (p8 + q < len) ? ww : 0.f;
            den += w[q];
        }
#pragma unroll
        for (int q = 0; q < 8; ++q) {
            float2 x0 = unpack_bf16(xw[q].x);
            float2 x1 = unpack_bf16(xw[q].y);
            a0 = fmaf(w[q], x0.x, a0);
            a1 = fmaf(w[q], x0.y, a1);
            a2 = fmaf(w[q], x1.x, a2);
            a3 = fmaf(w[q], x1.y, a3);
        }
    }
    float rd = 1.f / den;

    // ---- epilogue: residual + LN + relu; reductions within the 32-lane half.
    float4 bc4 = *(const float4*)&bc[c0];
    float y0 = a0 * rd + bc4.x + h4.x;
    float y1 = a1 * rd + bc4.y + h4.y;
    float y2 = a2 * rd + bc4.z + h4.z;
    float y3 = a3 * rd + bc4.w + h4.w;

    float s = y0 + y1 + y2 + y3;
#pragma unroll
    for (int off = 16; off >= 1; off >>= 1) s += __shfl_xor(s, off);
    float mean = s * (1.f / 128.f);
    float d0 = y0 - mean, d1 = y1 - mean, d2 = y2 - mean, d3 = y3 - mean;
    float vv = d0 * d0 + d1 * d1 + d2 * d2 + d3 * d3;
#pragma unroll
    for (int off = 16; off >= 1; off >>= 1) vv += __shfl_xor(vv, off);
    float rstd = rsqrtf(vv * (1.f / 128.f) + 1e-5f);
    float4 g4  = *(const float4*)&g[c0];
    float4 be4 = *(const float4*)&be[c0];
    float z0 = d0 * rstd * g4.x + be4.x;
    float z1 = d1 * rstd * g4.y + be4.y;
    float z2 = d2 * rstd * g4.z + be4.z;
    float z3 = d3 * rstd * g4.w + be4.w;
    float4 o;
    o.x = z0 > 0.f ? z0 : 0.f;
    o.y = z1 > 0.f ? z1 : 0.f;
    o.z = z2 > 0.f ? z2 : 0.f;
    o.w = z3 > 0.f ? z3 : 0.f;
    *(float4*)&h[(size_t)v * 128 + c0] = o;   // all 64 lanes write (2 rows per wave)
}

extern "C" void kernel_launch(void* const* d_in, const int* in_sizes, int n_in,
                              void* d_out, int out_size, void* d_ws, size_t ws_size,
                              hipStream_t stream) {
    const float* x      = (const float*)d_in[0];
    const int*   ei     = (const int*)d_in[1];
    const float* enc_w1 = (const float*)d_in[2];
    const float* enc_b1 = (const float*)d_in[3];
    const float* enc_w2 = (const float*)d_in[4];
    const float* enc_b2 = (const float*)d_in[5];
    const float *W[3], *as_[3], *ad_[3], *bc[3], *g[3], *be[3];
    for (int l = 0; l < 3; ++l) {
        W[l]   = (const float*)d_in[6 + l * 6 + 0];
        as_[l] = (const float*)d_in[6 + l * 6 + 1];
        ad_[l] = (const float*)d_in[6 + l * 6 + 2];
        bc[l]  = (const float*)d_in[6 + l * 6 + 3];
        g[l]   = (const float*)d_in[6 + l * 6 + 4];
        be[l]  = (const float*)d_in[6 + l * 6 + 5];
    }
    const float* imp_w1 = (const float*)d_in[24];
    const float* imp_b1 = (const float*)d_in[25];
    const float* imp_w2 = (const float*)d_in[26];
    const float* imp_b2 = (const float*)d_in[27];
    const float* tim_w1 = (const float*)d_in[28];
    const float* tim_b1 = (const float*)d_in[29];
    const float* tim_w2 = (const float*)d_in[30];
    const float* tim_b2 = (const float*)d_in[31];

    int* gcursor = (int*)d_ws;               // NPART
    int* rowptr  = gcursor + NPART + 64;     // NN+1
    int* colidx  = rowptr + NN + 1;          // ETOT (+8 slack)
    uintptr_t pb = (uintptr_t)(colidx + ETOT + 8);
    pb = (pb + 255) & ~(uintptr_t)255;
    unsigned* pbuf = (unsigned*)pb;          // NPART*PCAP (7.3 MB)
    uintptr_t fb = (uintptr_t)(pbuf + (size_t)NPART * PCAP);
    fb = (fb + 255) & ~(uintptr_t)255;
    float* es = (float*)fb;                  // NN*4
    float* ed = es + (size_t)NN * 4;         // NN*4
    float* h  = ed + (size_t)NN * 4;         // NN*128 fp32
    float* xpf = h + (size_t)NN * 128;       // region sized NN*128 floats
    unsigned* xpk = (unsigned*)xpf;          // packed bf16 uses first half
    unsigned short* wtb = (unsigned short*)(xpf + (size_t)NN * 128); // 5 x 16384 bf16 (160 KB)
    float* tmp = xpf;                        // enc1 scratch aliases (dead before xpk lives)

    wconv5_kernel<<<320, 256, 0, stream>>>(W[0], W[1], W[2], enc_w2, imp_w1, tim_w1, wtb, gcursor);
    pass1_kernel<<<512, 1024, 0, stream>>>(ei, gcursor, pbuf);
    pass2_kernel<<<NPART, 1024, 0, stream>>>(pbuf, gcursor, rowptr, colidx);

    const int GB64 = (NN + 63) / 64;
    gemm_small_kernel<128, true, FINDIM><<<(NN + 31) / 32, 256, 0, stream>>>(x, enc_w1, enc_b1, tmp, NN);
    gemm_mfma_bias_kernel<<<GB64, 256, 0, stream>>>(tmp, wtb + (size_t)3 * 16384, enc_b2, h, NN);

    for (int l = 0; l < 3; ++l) {
        gemm_mfma_kernel<<<GB64, 256, 0, stream>>>(h, wtb + (size_t)l * 16384, xpk,
                                                   as_[l], ad_[l], es, ed, NN);
        gat_kernel<<<(NN + 7) / 8, 256, 0, stream>>>(xpk, es, ed, rowptr, colidx, h,
                                                     bc[l], g[l], be[l]);
    }

    gemm_mfma_heads_kernel<<<GB64, 256, 0, stream>>>(h, wtb + (size_t)4 * 16384,
                                                     imp_b1, tim_b1, imp_w2, imp_b2,
                                                     tim_w2, tim_b2, (float*)d_out, NN);
}

// Round 11
// 507.671 us; speedup vs baseline: 1.1708x; 1.0062x over previous
//
#include <hip/hip_runtime.h>
#include <hip/hip_bf16.h>
#include <math.h>

#define NN 50000
#define EDGES 1600000
#define ETOT (EDGES + NN)
#define FINDIM 39
#define NPART 256
#define PSZ 196        // dsts per partition; 256*196 = 50176 >= NN
#define PCAP 7100      // capacity per partition (avg 6468, +7.9 sigma)
#define PCAP_PAD 8480  // padded slab: PCAP + 7*PSZ rounded up (max padded total 8472)
#define P1TILE 4096

typedef __attribute__((ext_vector_type(8))) short short8;
typedef __attribute__((ext_vector_type(4))) float floatx4;

__device__ __forceinline__ unsigned pack_bf16(float a, float b) {
    __hip_bfloat162 t;
    t.x = __float2bfloat16(a);
    t.y = __float2bfloat16(b);
    return *(unsigned*)&t;
}
__device__ __forceinline__ float2 unpack_bf16(unsigned w) {
    float2 r;
    r.x = __uint_as_float(w << 16);
    r.y = __uint_as_float(w & 0xffff0000u);
    return r;
}

__device__ __forceinline__ int src_at(const int* ei, int i, bool i32) {
    return i32 ? ei[i] : ei[2 * i];
}
__device__ __forceinline__ int dst_at(const int* ei, int i, bool i32) {
    return i32 ? ei[EDGES + i] : ei[2 * (EDGES + i)];
}

// ---------------- CSR pass 1 (1024 threads; unchanged from v16) ----------------
__global__ __launch_bounds__(1024) void pass1_kernel(const int* __restrict__ ei,
                                                     int* __restrict__ gcursor,
                                                     unsigned* __restrict__ pbuf) {
    __shared__ unsigned raw[P1TILE];
    __shared__ unsigned srt[P1TILE];
    __shared__ int pcnt[NPART], poff[NPART], pcur[NPART], gb[NPART];
    __shared__ int i32flag;
    int t = threadIdx.x;
    if (t == 0) i32flag = 0;
    __syncthreads();
    int chunk = (ETOT + gridDim.x - 1) / gridDim.x;
    int c0 = blockIdx.x * chunk;
    int c1 = c0 + chunk; if (c1 > ETOT) c1 = ETOT;
    int sb = c0 < EDGES - 64 ? c0 : 0;
    if (t < 64 && ei[2 * (sb + t) + 1] != 0) i32flag = 1;
    __syncthreads();
    bool i32 = (i32flag != 0);
    for (int t0 = c0; t0 < c1; t0 += P1TILE) {
        int tn = c1 - t0; if (tn > P1TILE) tn = P1TILE;
        if (t < NPART) { pcnt[t] = 0; pcur[t] = 0; }
        __syncthreads();
        for (int i = t; i < tn; i += 1024) {
            int e = t0 + i;
            int s, d;
            if (e < EDGES) { s = src_at(ei, e, i32); d = dst_at(ei, e, i32); }
            else { s = d = e - EDGES; }
            raw[i] = ((unsigned)s << 16) | (unsigned)d;
            atomicAdd(&pcnt[d / PSZ], 1);
        }
        __syncthreads();
        if (t < NPART) poff[t] = pcnt[t];
        __syncthreads();
        for (int off = 1; off < NPART; off <<= 1) {
            int v = (t < NPART && t >= off) ? poff[t - off] : 0;
            __syncthreads();
            if (t < NPART) poff[t] += v;
            __syncthreads();
        }
        if (t < NPART) {
            poff[t] -= pcnt[t];                       // exclusive
            gb[t] = atomicAdd(&gcursor[t], pcnt[t]);  // global base for this tile's run
        }
        __syncthreads();
        for (int i = t; i < tn; i += 1024) {
            unsigned r = raw[i];
            int part = (int)(r & 0xFFFFu) / PSZ;
            int pos = poff[part] + atomicAdd(&pcur[part], 1);
            srt[pos] = r;
        }
        __syncthreads();
        for (int i = t; i < tn; i += 1024) {
            unsigned r = srt[i];
            int part = (int)(r & 0xFFFFu) / PSZ;
            int gpos = gb[part] + (i - poff[part]);
            if (gpos < PCAP) pbuf[(size_t)part * PCAP + gpos] = r;
        }
        __syncthreads();
    }
}

// ---------------- CSR pass 2: padded rows (mult of 8, pads = NN dummy), fixed slabs,
// rowdesc = start | (alen/8)<<24. No cross-partition scan. wconv5 folded into tail. ----------------
__global__ __launch_bounds__(1024) void pass2_kernel(const unsigned* __restrict__ pbuf,
                                                     const int* __restrict__ gcursor,
                                                     unsigned* __restrict__ rowdesc,
                                                     int* __restrict__ colidx,
                                                     const float* __restrict__ W0,
                                                     const float* __restrict__ W1,
                                                     const float* __restrict__ W2,
                                                     const float* __restrict__ ew2,
                                                     const float* __restrict__ iw1,
                                                     const float* __restrict__ tw1,
                                                     unsigned short* __restrict__ wtb) {
    __shared__ unsigned recs[PCAP];                 // 28.4 KB
    __shared__ int lhist[PSZ], lexcl[PSZ], lcur[PSZ];
    int p = blockIdx.x;
    int t = threadIdx.x;
    int n = gcursor[p]; if (n > PCAP) n = PCAP;
    int slab = p * PCAP_PAD;
    int d0 = p * PSZ;
    int nd = NN - d0; if (nd > PSZ) nd = PSZ;
    if (nd < 0) nd = 0;
    for (int i = t; i < nd; i += 1024) { lhist[i] = 0; lcur[i] = 0; }
    __syncthreads();
    for (int i = t; i < n; i += 1024) {
        unsigned r = pbuf[(size_t)p * PCAP + i];
        recs[i] = r;
        atomicAdd(&lhist[(int)(r & 0xFFFFu) - d0], 1);
    }
    __syncthreads();
    // scan of PADDED counts (exclusive)
    for (int i = t; i < nd; i += 1024) lexcl[i] = min((lhist[i] + 7) & ~7, 2040);
    __syncthreads();
    for (int off = 1; off < PSZ; off <<= 1) {
        int a0 = 0;
        if (t < nd && t >= off) a0 = lexcl[t - off];
        __syncthreads();
        if (t < nd) lexcl[t] += a0;
        __syncthreads();
    }
    for (int i = t; i < nd; i += 1024) {
        int pl = min((lhist[i] + 7) & ~7, 2040);
        lexcl[i] -= pl;                              // exclusive padded offset
        rowdesc[d0 + i] = (unsigned)(slab + lexcl[i]) | ((unsigned)(pl >> 3) << 24);
    }
    __syncthreads();
    // scatter true entries
    for (int i = t; i < n; i += 1024) {
        unsigned r = recs[i];
        int li = (int)(r & 0xFFFFu) - d0;
        int pos = slab + lexcl[li] + atomicAdd(&lcur[li], 1);
        colidx[pos] = (int)(r >> 16);
    }
    // pad fill (disjoint from true region; no barrier needed)
    for (int i = t; i < nd; i += 1024) {
        int pl = min((lhist[i] + 7) & ~7, 2040);
        int base = slab + lexcl[i];
        for (int k = lhist[i]; k < pl; ++k) colidx[base + k] = NN;
    }
    // ---- wconv5 tail: 5 matrices -> bf16 transposed wtb[m][c][k] (81920 elements)
    int widx = p * 1024 + t;
    if (widx < 5 * 16384) {
        int m = widx >> 14;
        int r = widx & 16383;
        int c = r >> 7, k = r & 127;
        float v;
        if (m == 0) v = W0[(size_t)k * 128 + c];
        else if (m == 1) v = W1[(size_t)k * 128 + c];
        else if (m == 2) v = W2[(size_t)k * 128 + c];
        else if (m == 3) v = ew2[(size_t)k * 128 + c];
        else v = (c < 64) ? iw1[(size_t)k * 64 + c] : tw1[(size_t)k * 64 + (c - 64)];
        unsigned pk = pack_bf16(v, 0.f);
        wtb[widx] = (unsigned short)(pk & 0xffffu);
    }
}

// ---------------- generic GEMM (K=39 encoder-1 only; K compile-time) ----------------
template <int NC, bool RELU, int K>
__global__ __launch_bounds__(256) void gemm_small_kernel(const float* __restrict__ A,
                                                         const float* __restrict__ B,
                                                         const float* __restrict__ bias,
                                                         float* __restrict__ C, int M) {
    constexpr int TM = 32;
    constexpr int GROUPS = 256 / NC;
    constexpr int RPG = TM / GROUPS;
    constexpr int KC = 64;
    __shared__ float As[TM * 128];
    __shared__ float Bs[KC * NC];
    int t = threadIdx.x;
    int i0 = blockIdx.x * TM;

    int rows = M - i0; if (rows > TM) rows = TM;
    for (int idx = t; idx < rows * K; idx += 256) {
        int r = idx / K, k = idx - r * K;
        As[r * K + k] = A[(size_t)(i0 + r) * K + k];
    }

    int col = t % NC, grp = t / NC;
    int rg0 = grp * RPG;
    float acc[RPG];
#pragma unroll
    for (int r = 0; r < RPG; ++r) acc[r] = 0.f;

    for (int k0 = 0; k0 < K; k0 += KC) {
        int kc = K - k0; if (kc > KC) kc = KC;
        __syncthreads();
        for (int idx = t; idx < kc * NC; idx += 256) Bs[idx] = B[(size_t)k0 * NC + idx];
        __syncthreads();
        for (int k = 0; k < kc; ++k) {
            float bv = Bs[k * NC + col];
#pragma unroll
            for (int r = 0; r < RPG; ++r) acc[r] += As[(rg0 + r) * K + k0 + k] * bv;
        }
    }

    float bb = bias ? bias[col] : 0.f;
#pragma unroll
    for (int r = 0; r < RPG; ++r) {
        int i = i0 + rg0 + r;
        if (i < M) {
            float v = acc[r] + bb;
            if (RELU) v = v > 0.f ? v : 0.f;
            C[(size_t)i * NC + col] = v;
        }
    }
}

// ---------------- shared MFMA core: acc[n] = bf16(Arow) @ wtb, 16 rows x 128 cols per wave ----------------
__device__ __forceinline__ void mfma_core(const float* __restrict__ A, int arow, int valid,
                                          const unsigned short* __restrict__ wtb,
                                          int c, int grp, floatx4 acc[8]) {
#pragma unroll
    for (int n = 0; n < 8; ++n) acc[n] = (floatx4){0.f, 0.f, 0.f, 0.f};
    short8 af[4];
#pragma unroll
    for (int kc = 0; kc < 4; ++kc) {
        float4 f0 = make_float4(0.f, 0.f, 0.f, 0.f), f1 = f0;
        if (valid) {
            const float* hp = &A[(size_t)arow * 128 + (kc << 5) + (grp << 3)];
            f0 = *(const float4*)hp;
            f1 = *(const float4*)(hp + 4);
        }
        unsigned pk[4];
        pk[0] = pack_bf16(f0.x, f0.y);
        pk[1] = pack_bf16(f0.z, f0.w);
        pk[2] = pack_bf16(f1.x, f1.y);
        pk[3] = pack_bf16(f1.z, f1.w);
        af[kc] = *(short8*)pk;
    }
#pragma unroll
    for (int kc = 0; kc < 4; ++kc) {
#pragma unroll
        for (int n = 0; n < 8; ++n) {
            short8 bf = *(const short8*)&wtb[(size_t)(((n << 4) + c) * 128 + (kc << 5) + (grp << 3))];
            acc[n] = __builtin_amdgcn_mfma_f32_16x16x32_bf16(af[kc], bf, acc[n], 0, 0, 0);
        }
    }
}

// ---------------- MFMA GEMM (W layers): xp = bf16(h) @ W; epilogue xpk + es/ed.
// Block 0 also maintains the dummy row NN: xpk row NN = 0, es row NN = -1e30
// (pads in the padded CSR hit these: w = exp(-inf) = 0, 0 * finite = 0).
__global__ __launch_bounds__(256) void gemm_mfma_kernel(const float* __restrict__ H,
                                                        const unsigned short* __restrict__ wtb,
                                                        unsigned* __restrict__ XP,
                                                        const float* __restrict__ a_s,
                                                        const float* __restrict__ a_d,
                                                        float* __restrict__ es,
                                                        float* __restrict__ ed, int M) {
    int t = threadIdx.x;
    int w = t >> 6, l = t & 63;
    int c = l & 15, grp = l >> 4;
    int i0 = blockIdx.x * 64 + w * 16;
    int arow = i0 + c;

    if (blockIdx.x == 0) {
        if (t < 64) XP[(size_t)NN * 64 + t] = 0u;
        else if (t < 68) es[(size_t)NN * 4 + (t - 64)] = -1e30f;
    }

    floatx4 acc[8];
    mfma_core(H, arow, arow < M, wtb, c, grp, acc);

    float asv[8], adv[8];
#pragma unroll
    for (int n = 0; n < 8; ++n) { asv[n] = a_s[(n << 4) + c]; adv[n] = a_d[(n << 4) + c]; }

    float sp[4][4], dp[4][4];   // [r][head]
#pragma unroll
    for (int r = 0; r < 4; ++r)
#pragma unroll
        for (int hd = 0; hd < 4; ++hd) { sp[r][hd] = 0.f; dp[r][hd] = 0.f; }

#pragma unroll
    for (int n = 0; n < 8; ++n) {
#pragma unroll
        for (int r = 0; r < 4; ++r) {
            float vv = acc[n][r];
            float pv = __shfl_xor(vv, 1);
            int row = i0 + (grp << 2) + r;
            if (!(c & 1) && row < M)
                XP[(size_t)row * 64 + (n << 3) + (c >> 1)] = pack_bf16(vv, pv);
            sp[r][n >> 1] = fmaf(vv, asv[n], sp[r][n >> 1]);
            dp[r][n >> 1] = fmaf(vv, adv[n], dp[r][n >> 1]);
        }
    }
#pragma unroll
    for (int r = 0; r < 4; ++r)
#pragma unroll
        for (int hd = 0; hd < 4; ++hd) {
            float s = sp[r][hd], d = dp[r][hd];
#pragma unroll
            for (int off = 1; off <= 8; off <<= 1) {
                s += __shfl_xor(s, off);
                d += __shfl_xor(d, off);
            }
            sp[r][hd] = s; dp[r][hd] = d;
        }
    if (c < 4) {
#pragma unroll
        for (int r = 0; r < 4; ++r) {
            int row = i0 + (grp << 2) + r;
            if (row < M) {
                float s = (c == 0) ? sp[r][0] : (c == 1) ? sp[r][1] : (c == 2) ? sp[r][2] : sp[r][3];
                float d = (c == 0) ? dp[r][0] : (c == 1) ? dp[r][1] : (c == 2) ? dp[r][2] : dp[r][3];
                es[(size_t)row * 4 + c] = s;
                ed[(size_t)row * 4 + c] = d;
            }
        }
    }
}

// ---------------- MFMA GEMM (enc2): h = bf16(tmp) @ enc_w2 + b, fp32 out ----------------
__global__ __launch_bounds__(256) void gemm_mfma_bias_kernel(const float* __restrict__ A,
                                                             const unsigned short* __restrict__ wtb,
                                                             const float* __restrict__ bias,
                                                             float* __restrict__ C, int M) {
    int t = threadIdx.x;
    int w = t >> 6, l = t & 63;
    int c = l & 15, grp = l >> 4;
    int i0 = blockIdx.x * 64 + w * 16;
    int arow = i0 + c;

    floatx4 acc[8];
    mfma_core(A, arow, arow < M, wtb, c, grp, acc);

    float bv[8];
#pragma unroll
    for (int n = 0; n < 8; ++n) bv[n] = bias[(n << 4) + c];
#pragma unroll
    for (int n = 0; n < 8; ++n)
#pragma unroll
        for (int r = 0; r < 4; ++r) {
            int row = i0 + (grp << 2) + r;
            if (row < M) C[(size_t)row * 128 + (n << 4) + c] = acc[n][r] + bv[n];
        }
}

// ---------------- MFMA heads: layer1 via MFMA (128 virtual cols), layer2 in epilogue ----------------
__global__ __launch_bounds__(256) void gemm_mfma_heads_kernel(const float* __restrict__ H,
                                                              const unsigned short* __restrict__ wtb,
                                                              const float* __restrict__ ib1,
                                                              const float* __restrict__ tb1,
                                                              const float* __restrict__ iw2,
                                                              const float* __restrict__ ib2,
                                                              const float* __restrict__ tw2,
                                                              const float* __restrict__ tb2,
                                                              float* __restrict__ out, int M) {
    int t = threadIdx.x;
    int w = t >> 6, l = t & 63;
    int c = l & 15, grp = l >> 4;
    int i0 = blockIdx.x * 64 + w * 16;
    int arow = i0 + c;

    floatx4 acc[8];
    mfma_core(H, arow, arow < M, wtb, c, grp, acc);

    float iw2v[4][3], tw2v[4][2], ib1v[4], tb1v[4];
#pragma unroll
    for (int n = 0; n < 4; ++n) {
        int lc = (n << 4) + c;
        ib1v[n] = ib1[lc];
        tb1v[n] = tb1[lc];
#pragma unroll
        for (int o = 0; o < 3; ++o) iw2v[n][o] = iw2[lc * 3 + o];
#pragma unroll
        for (int d = 0; d < 2; ++d) tw2v[n][d] = tw2[lc * 2 + d];
    }

    float pi[4][3], pt[4][2];
#pragma unroll
    for (int r = 0; r < 4; ++r) {
#pragma unroll
        for (int o = 0; o < 3; ++o) pi[r][o] = 0.f;
#pragma unroll
        for (int d = 0; d < 2; ++d) pt[r][d] = 0.f;
    }
#pragma unroll
    for (int n = 0; n < 4; ++n)
#pragma unroll
        for (int r = 0; r < 4; ++r) {
            float vi = acc[n][r] + ib1v[n];     vi = vi > 0.f ? vi : 0.f;
            float vt = acc[n + 4][r] + tb1v[n]; vt = vt > 0.f ? vt : 0.f;
#pragma unroll
            for (int o = 0; o < 3; ++o) pi[r][o] = fmaf(vi, iw2v[n][o], pi[r][o]);
#pragma unroll
            for (int d = 0; d < 2; ++d) pt[r][d] = fmaf(vt, tw2v[n][d], pt[r][d]);
        }
#pragma unroll
    for (int r = 0; r < 4; ++r) {
#pragma unroll
        for (int o = 0; o < 3; ++o) {
            float s = pi[r][o];
#pragma unroll
            for (int off = 1; off <= 8; off <<= 1) s += __shfl_xor(s, off);
            pi[r][o] = s;
        }
#pragma unroll
        for (int d = 0; d < 2; ++d) {
            float s = pt[r][d];
#pragma unroll
            for (int off = 1; off <= 8; off <<= 1) s += __shfl_xor(s, off);
            pt[r][d] = s;
        }
    }
    if (c == 0) {
#pragma unroll
        for (int r = 0; r < 4; ++r) {
            int row = i0 + (grp << 2) + r;
            if (row < M) {
#pragma unroll
                for (int o = 0; o < 3; ++o) out[(size_t)row * 3 + o] = pi[r][o] + ib2[o];
#pragma unroll
                for (int d = 0; d < 2; ++d) {
                    float a = pt[r][d] + tb2[d];
                    float sp = a > 20.f ? a : log1pf(__expf(a));
                    out[(size_t)(NN * 3) + (size_t)row * 2 + d] = sp;
                }
            }
        }
    }
}

// ---------------- gat v17: v10 gather structure + padded CSR (no clamp, no tail select,
// no cross-half shfl, single rowdesc load). Pads point at dummy node NN whose es=-1e30
// (w=0 exactly) and xpk row=0 (0*0=0) -> bit-identical accumulation.
__global__ __launch_bounds__(256, 6) void gat_kernel(const unsigned* __restrict__ xpk,
                                                     const float* __restrict__ es,
                                                     const float* __restrict__ ed,
                                                     const unsigned* __restrict__ rowdesc,
                                                     const int* __restrict__ colidx,
                                                     float* __restrict__ h,   // in-out (residual)
                                                     const float* __restrict__ bc,
                                                     const float* __restrict__ g,
                                                     const float* __restrict__ be) {
    int wv = threadIdx.x >> 6, l = threadIdx.x & 63;
    int hf = l >> 5;                        // which node of the pair
    int lh = l & 31;
    int hd = lh >> 3;                       // head 0..3
    int j  = lh & 7;                        // 0..7
    int v = blockIdx.x * 8 + wv * 2 + hf;   // grid covers NN exactly (6250*8=50000)
    if (v >= NN) return;                    // defensive
    unsigned dsc = rowdesc[v];
    int s0 = (int)(dsc & 0xFFFFFFu);
    int alen = (int)(dsc >> 24) << 3;       // padded length, multiple of 8, >= 8
    int c0 = (hd << 5) + (j << 2);          // 4 channels owned by this lane
    int xsel = (hd << 4) + (j << 1);        // even dword index into 64-dword xpk row
    float edv = ed[((unsigned)v << 2) + hd];

    // hoisted: residual row load overlaps the whole gather loop
    float4 h4 = *(const float4*)&h[(size_t)v * 128 + c0];

    float a0 = 0.f, a1 = 0.f, a2 = 0.f, a3 = 0.f, den = 0.f;
    for (int p8 = 0; p8 < alen; p8 += 8) {  // divergent between halves: exec-masked
        int u[8];
#pragma unroll
        for (int q = 0; q < 8; ++q) u[q] = colidx[s0 + p8 + q];
        uint2 xw[8];
#pragma unroll
        for (int q = 0; q < 8; ++q)
            xw[q] = *(const uint2*)&xpk[((unsigned)u[q] << 6) + xsel];
        float w[8];
#pragma unroll
        for (int q = 0; q < 8; ++q) {
            float e = es[((unsigned)u[q] << 2) + hd] + edv;
            e = fmaxf(e, 0.2f * e);         // leaky_relu, slope<1 => max form
            w[q] = __expf(e);               // pads: exp(-huge) = exactly 0
            den += w[q];
        }
#pragma unroll
        for (int q = 0; q < 8; ++q) {
            float2 x0 = unpack_bf16(xw[q].x);
            float2 x1 = unpack_bf16(xw[q].y);
            a0 = fmaf(w[q], x0.x, a0);
            a1 = fmaf(w[q], x0.y, a1);
            a2 = fmaf(w[q], x1.x, a2);
            a3 = fmaf(w[q], x1.y, a3);
        }
    }
    float rd = 1.f / den;

    // ---- epilogue: residual + LN + relu; reductions within the 32-lane half.
    float4 bc4 = *(const float4*)&bc[c0];
    float y0 = a0 * rd + bc4.x + h4.x;
    float y1 = a1 * rd + bc4.y + h4.y;
    float y2 = a2 * rd + bc4.z + h4.z;
    float y3 = a3 * rd + bc4.w + h4.w;

    float s = y0 + y1 + y2 + y3;
#pragma unroll
    for (int off = 16; off >= 1; off >>= 1) s += __shfl_xor(s, off);
    float mean = s * (1.f / 128.f);
    float d0 = y0 - mean, d1 = y1 - mean, d2 = y2 - mean, d3 = y3 - mean;
    float vv = d0 * d0 + d1 * d1 + d2 * d2 + d3 * d3;
#pragma unroll
    for (int off = 16; off >= 1; off >>= 1) vv += __shfl_xor(vv, off);
    float rstd = rsqrtf(vv * (1.f / 128.f) + 1e-5f);
    float4 g4  = *(const float4*)&g[c0];
    float4 be4 = *(const float4*)&be[c0];
    float z0 = d0 * rstd * g4.x + be4.x;
    float z1 = d1 * rstd * g4.y + be4.y;
    float z2 = d2 * rstd * g4.z + be4.z;
    float z3 = d3 * rstd * g4.w + be4.w;
    float4 o;
    o.x = z0 > 0.f ? z0 : 0.f;
    o.y = z1 > 0.f ? z1 : 0.f;
    o.z = z2 > 0.f ? z2 : 0.f;
    o.w = z3 > 0.f ? z3 : 0.f;
    *(float4*)&h[(size_t)v * 128 + c0] = o;   // all 64 lanes write (2 rows per wave)
}

extern "C" void kernel_launch(void* const* d_in, const int* in_sizes, int n_in,
                              void* d_out, int out_size, void* d_ws, size_t ws_size,
                              hipStream_t stream) {
    const float* x      = (const float*)d_in[0];
    const int*   ei     = (const int*)d_in[1];
    const float* enc_w1 = (const float*)d_in[2];
    const float* enc_b1 = (const float*)d_in[3];
    const float* enc_w2 = (const float*)d_in[4];
    const float* enc_b2 = (const float*)d_in[5];
    const float *W[3], *as_[3], *ad_[3], *bc[3], *g[3], *be[3];
    for (int l = 0; l < 3; ++l) {
        W[l]   = (const float*)d_in[6 + l * 6 + 0];
        as_[l] = (const float*)d_in[6 + l * 6 + 1];
        ad_[l] = (const float*)d_in[6 + l * 6 + 2];
        bc[l]  = (const float*)d_in[6 + l * 6 + 3];
        g[l]   = (const float*)d_in[6 + l * 6 + 4];
        be[l]  = (const float*)d_in[6 + l * 6 + 5];
    }
    const float* imp_w1 = (const float*)d_in[24];
    const float* imp_b1 = (const float*)d_in[25];
    const float* imp_w2 = (const float*)d_in[26];
    const float* imp_b2 = (const float*)d_in[27];
    const float* tim_w1 = (const float*)d_in[28];
    const float* tim_b1 = (const float*)d_in[29];
    const float* tim_w2 = (const float*)d_in[30];
    const float* tim_b2 = (const float*)d_in[31];

    int* gcursor = (int*)d_ws;                             // NPART (+64 pad)
    unsigned* rowdesc = (unsigned*)(gcursor + NPART + 64); // NN
    int* colidx = (int*)(rowdesc + NN);                    // NPART*PCAP_PAD (8.7 MB)
    uintptr_t pb = (uintptr_t)(colidx + (size_t)NPART * PCAP_PAD);
    pb = (pb + 255) & ~(uintptr_t)255;
    unsigned* pbuf = (unsigned*)pb;          // NPART*PCAP (7.3 MB)
    uintptr_t fb = (uintptr_t)(pbuf + (size_t)NPART * PCAP);
    fb = (fb + 255) & ~(uintptr_t)255;
    float* es = (float*)fb;                  // (NN+1)*4 (+pad)
    float* ed = es + (size_t)NN * 4 + 64;    // NN*4
    float* h  = ed + (size_t)NN * 4;         // NN*128 fp32
    float* xpf = h + (size_t)NN * 128;       // region sized NN*128 floats
    unsigned* xpk = (unsigned*)xpf;          // packed bf16 xp, (NN+1)*64 dwords
    unsigned short* wtb = (unsigned short*)(xpf + (size_t)NN * 128); // 5 x 16384 bf16 (160 KB)
    float* tmp = xpf;                        // enc1 scratch aliases (dead before xpk row NN zeroed)

    hipMemsetAsync(gcursor, 0, NPART * sizeof(int), stream);
    pass1_kernel<<<512, 1024, 0, stream>>>(ei, gcursor, pbuf);
    pass2_kernel<<<NPART, 1024, 0, stream>>>(pbuf, gcursor, rowdesc, colidx,
                                             W[0], W[1], W[2], enc_w2, imp_w1, tim_w1, wtb);

    const int GB64 = (NN + 63) / 64;
    gemm_small_kernel<128, true, FINDIM><<<(NN + 31) / 32, 256, 0, stream>>>(x, enc_w1, enc_b1, tmp, NN);
    gemm_mfma_bias_kernel<<<GB64, 256, 0, stream>>>(tmp, wtb + (size_t)3 * 16384, enc_b2, h, NN);

    for (int l = 0; l < 3; ++l) {
        gemm_mfma_kernel<<<GB64, 256, 0, stream>>>(h, wtb + (size_t)l * 16384, xpk,
                                                   as_[l], ad_[l], es, ed, NN);
        gat_kernel<<<(NN + 7) / 8, 256, 0, stream>>>(xpk, es, ed, rowdesc, colidx, h,
                                                     bc[l], g[l], be[l]);
    }

    gemm_mfma_heads_kernel<<<GB64, 256, 0, stream>>>(h, wtb + (size_t)4 * 16384,
                                                     imp_b1, tim_b1, imp_w2, imp_b2,
                                                     tim_w2, tim_b2, (float*)d_out, NN);
}

// Round 12
// 498.997 us; speedup vs baseline: 1.1912x; 1.0174x over previous
//
#include <hip/hip_runtime.h>
#include <hip/hip_bf16.h>
#include <math.h>

#define NN 50000
#define EDGES 1600000
#define ETOT (EDGES + NN)
#define FINDIM 39
#define NPART 256
#define PSZ 196        // dsts per partition; 256*196 = 50176 >= NN
#define PCAP 7100      // capacity per partition (avg 6468, +7.9 sigma)
#define PCAP_PAD 8480  // padded slab: PCAP + 7*PSZ rounded up (max padded total 8472)
#define P1TILE 4096

typedef __attribute__((ext_vector_type(8))) short short8;
typedef __attribute__((ext_vector_type(4))) float floatx4;

__device__ __forceinline__ unsigned pack_bf16(float a, float b) {
    __hip_bfloat162 t;
    t.x = __float2bfloat16(a);
    t.y = __float2bfloat16(b);
    return *(unsigned*)&t;
}
__device__ __forceinline__ float2 unpack_bf16(unsigned w) {
    float2 r;
    r.x = __uint_as_float(w << 16);
    r.y = __uint_as_float(w & 0xffff0000u);
    return r;
}

__device__ __forceinline__ int src_at(const int* ei, int i, bool i32) {
    return i32 ? ei[i] : ei[2 * i];
}
__device__ __forceinline__ int dst_at(const int* ei, int i, bool i32) {
    return i32 ? ei[EDGES + i] : ei[2 * (EDGES + i)];
}

// ---------------- CSR pass 1 (1024 threads; unchanged) ----------------
__global__ __launch_bounds__(1024) void pass1_kernel(const int* __restrict__ ei,
                                                     int* __restrict__ gcursor,
                                                     unsigned* __restrict__ pbuf) {
    __shared__ unsigned raw[P1TILE];
    __shared__ unsigned srt[P1TILE];
    __shared__ int pcnt[NPART], poff[NPART], pcur[NPART], gb[NPART];
    __shared__ int i32flag;
    int t = threadIdx.x;
    if (t == 0) i32flag = 0;
    __syncthreads();
    int chunk = (ETOT + gridDim.x - 1) / gridDim.x;
    int c0 = blockIdx.x * chunk;
    int c1 = c0 + chunk; if (c1 > ETOT) c1 = ETOT;
    int sb = c0 < EDGES - 64 ? c0 : 0;
    if (t < 64 && ei[2 * (sb + t) + 1] != 0) i32flag = 1;
    __syncthreads();
    bool i32 = (i32flag != 0);
    for (int t0 = c0; t0 < c1; t0 += P1TILE) {
        int tn = c1 - t0; if (tn > P1TILE) tn = P1TILE;
        if (t < NPART) { pcnt[t] = 0; pcur[t] = 0; }
        __syncthreads();
        for (int i = t; i < tn; i += 1024) {
            int e = t0 + i;
            int s, d;
            if (e < EDGES) { s = src_at(ei, e, i32); d = dst_at(ei, e, i32); }
            else { s = d = e - EDGES; }
            raw[i] = ((unsigned)s << 16) | (unsigned)d;
            atomicAdd(&pcnt[d / PSZ], 1);
        }
        __syncthreads();
        if (t < NPART) poff[t] = pcnt[t];
        __syncthreads();
        for (int off = 1; off < NPART; off <<= 1) {
            int v = (t < NPART && t >= off) ? poff[t - off] : 0;
            __syncthreads();
            if (t < NPART) poff[t] += v;
            __syncthreads();
        }
        if (t < NPART) {
            poff[t] -= pcnt[t];                       // exclusive
            gb[t] = atomicAdd(&gcursor[t], pcnt[t]);  // global base for this tile's run
        }
        __syncthreads();
        for (int i = t; i < tn; i += 1024) {
            unsigned r = raw[i];
            int part = (int)(r & 0xFFFFu) / PSZ;
            int pos = poff[part] + atomicAdd(&pcur[part], 1);
            srt[pos] = r;
        }
        __syncthreads();
        for (int i = t; i < tn; i += 1024) {
            unsigned r = srt[i];
            int part = (int)(r & 0xFFFFu) / PSZ;
            int gpos = gb[part] + (i - poff[part]);
            if (gpos < PCAP) pbuf[(size_t)part * PCAP + gpos] = r;
        }
        __syncthreads();
    }
}

// ---------------- CSR pass 2: padded rows (unchanged from v17) ----------------
__global__ __launch_bounds__(1024) void pass2_kernel(const unsigned* __restrict__ pbuf,
                                                     const int* __restrict__ gcursor,
                                                     unsigned* __restrict__ rowdesc,
                                                     int* __restrict__ colidx,
                                                     const float* __restrict__ W0,
                                                     const float* __restrict__ W1,
                                                     const float* __restrict__ W2,
                                                     const float* __restrict__ ew2,
                                                     const float* __restrict__ iw1,
                                                     const float* __restrict__ tw1,
                                                     unsigned short* __restrict__ wtb) {
    __shared__ unsigned recs[PCAP];                 // 28.4 KB
    __shared__ int lhist[PSZ], lexcl[PSZ], lcur[PSZ];
    int p = blockIdx.x;
    int t = threadIdx.x;
    int n = gcursor[p]; if (n > PCAP) n = PCAP;
    int slab = p * PCAP_PAD;
    int d0 = p * PSZ;
    int nd = NN - d0; if (nd > PSZ) nd = PSZ;
    if (nd < 0) nd = 0;
    for (int i = t; i < nd; i += 1024) { lhist[i] = 0; lcur[i] = 0; }
    __syncthreads();
    for (int i = t; i < n; i += 1024) {
        unsigned r = pbuf[(size_t)p * PCAP + i];
        recs[i] = r;
        atomicAdd(&lhist[(int)(r & 0xFFFFu) - d0], 1);
    }
    __syncthreads();
    for (int i = t; i < nd; i += 1024) lexcl[i] = min((lhist[i] + 7) & ~7, 2040);
    __syncthreads();
    for (int off = 1; off < PSZ; off <<= 1) {
        int a0 = 0;
        if (t < nd && t >= off) a0 = lexcl[t - off];
        __syncthreads();
        if (t < nd) lexcl[t] += a0;
        __syncthreads();
    }
    for (int i = t; i < nd; i += 1024) {
        int pl = min((lhist[i] + 7) & ~7, 2040);
        lexcl[i] -= pl;                              // exclusive padded offset
        rowdesc[d0 + i] = (unsigned)(slab + lexcl[i]) | ((unsigned)(pl >> 3) << 24);
    }
    __syncthreads();
    for (int i = t; i < n; i += 1024) {
        unsigned r = recs[i];
        int li = (int)(r & 0xFFFFu) - d0;
        int pos = slab + lexcl[li] + atomicAdd(&lcur[li], 1);
        colidx[pos] = (int)(r >> 16);
    }
    for (int i = t; i < nd; i += 1024) {
        int pl = min((lhist[i] + 7) & ~7, 2040);
        int base = slab + lexcl[i];
        for (int k = lhist[i]; k < pl; ++k) colidx[base + k] = NN;
    }
    // ---- wconv5 tail: 5 matrices -> bf16 transposed wtb[m][c][k] (81920 elements)
    int widx = p * 1024 + t;
    if (widx < 5 * 16384) {
        int m = widx >> 14;
        int r = widx & 16383;
        int c = r >> 7, k = r & 127;
        float v;
        if (m == 0) v = W0[(size_t)k * 128 + c];
        else if (m == 1) v = W1[(size_t)k * 128 + c];
        else if (m == 2) v = W2[(size_t)k * 128 + c];
        else if (m == 3) v = ew2[(size_t)k * 128 + c];
        else v = (c < 64) ? iw1[(size_t)k * 64 + c] : tw1[(size_t)k * 64 + (c - 64)];
        unsigned pk = pack_bf16(v, 0.f);
        wtb[widx] = (unsigned short)(pk & 0xffffu);
    }
}

// ---------------- fused encoder: enc1 (VALU, K=39) -> LDS bf16 -> enc2 MFMA -> h ----------------
// Same k-order and same bf16 quantization point as the unfused pair => bit-identical h.
__global__ __launch_bounds__(256) void gemm_enc_fused_kernel(const float* __restrict__ x,
                                                             const float* __restrict__ w1,
                                                             const float* __restrict__ b1,
                                                             const unsigned short* __restrict__ wtb,
                                                             const float* __restrict__ b2,
                                                             float* __restrict__ H, int M) {
    __shared__ float lx[64 * 40];            // 10.2 KB, x rows (pad 39->40)
    __shared__ unsigned short tb[64 * 136];  // 17.4 KB, bf16 enc1 out (stride 68 dwords)
    int t = threadIdx.x;
    int i0 = blockIdx.x * 64;

    for (int idx = t; idx < 64 * FINDIM; idx += 256) {
        int r = idx / FINDIM, k = idx - r * FINDIM;
        int row = i0 + r;
        lx[r * 40 + k] = (row < M) ? x[(size_t)row * FINDIM + k] : 0.f;
    }
    __syncthreads();

    // enc1: thread owns (col = t&127) for 32 rows (rgrp = t>>7)
    int col = t & 127, rgrp = t >> 7;
    float w1c[FINDIM];
#pragma unroll
    for (int k = 0; k < FINDIM; ++k) w1c[k] = w1[(size_t)k * 128 + col];
    float b1c = b1[col];
    for (int r = 0; r < 32; ++r) {
        int lr = rgrp * 32 + r;
        float acc = b1c;
#pragma unroll
        for (int k4 = 0; k4 < 9; ++k4) {     // 36 of 39 via float4 broadcast reads
            float4 xv = *(const float4*)&lx[lr * 40 + k4 * 4];
            acc = fmaf(xv.x, w1c[k4 * 4 + 0], acc);
            acc = fmaf(xv.y, w1c[k4 * 4 + 1], acc);
            acc = fmaf(xv.z, w1c[k4 * 4 + 2], acc);
            acc = fmaf(xv.w, w1c[k4 * 4 + 3], acc);
        }
#pragma unroll
        for (int k = 36; k < FINDIM; ++k) acc = fmaf(lx[lr * 40 + k], w1c[k], acc);
        acc = acc > 0.f ? acc : 0.f;
        unsigned p = pack_bf16(acc, 0.f);
        tb[lr * 136 + col] = (unsigned short)(p & 0xffffu);
    }
    __syncthreads();

    // enc2: MFMA, A-frags from LDS (stride-68-dword rows => 2-way-free bank pattern)
    int w = t >> 6, l = t & 63;
    int c = l & 15, grp = l >> 4;
    floatx4 acc[8];
#pragma unroll
    for (int n = 0; n < 8; ++n) acc[n] = (floatx4){0.f, 0.f, 0.f, 0.f};
    short8 af[4];
#pragma unroll
    for (int kc = 0; kc < 4; ++kc)
        af[kc] = *(short8*)&tb[(w * 16 + c) * 136 + (kc << 5) + (grp << 3)];
#pragma unroll
    for (int kc = 0; kc < 4; ++kc) {
#pragma unroll
        for (int n = 0; n < 8; ++n) {
            short8 bf = *(const short8*)&wtb[(size_t)(((n << 4) + c) * 128 + (kc << 5) + (grp << 3))];
            acc[n] = __builtin_amdgcn_mfma_f32_16x16x32_bf16(af[kc], bf, acc[n], 0, 0, 0);
        }
    }
    int i0w = i0 + w * 16;
    float bv[8];
#pragma unroll
    for (int n = 0; n < 8; ++n) bv[n] = b2[(n << 4) + c];
#pragma unroll
    for (int n = 0; n < 8; ++n)
#pragma unroll
        for (int r = 0; r < 4; ++r) {
            int row = i0w + (grp << 2) + r;
            if (row < M) H[(size_t)row * 128 + (n << 4) + c] = acc[n][r] + bv[n];
        }
}

// ---------------- shared MFMA core (A from global fp32, packed in-register) ----------------
__device__ __forceinline__ void mfma_core(const float* __restrict__ A, int arow, int valid,
                                          const unsigned short* __restrict__ wtb,
                                          int c, int grp, floatx4 acc[8]) {
#pragma unroll
    for (int n = 0; n < 8; ++n) acc[n] = (floatx4){0.f, 0.f, 0.f, 0.f};
    short8 af[4];
#pragma unroll
    for (int kc = 0; kc < 4; ++kc) {
        float4 f0 = make_float4(0.f, 0.f, 0.f, 0.f), f1 = f0;
        if (valid) {
            const float* hp = &A[(size_t)arow * 128 + (kc << 5) + (grp << 3)];
            f0 = *(const float4*)hp;
            f1 = *(const float4*)(hp + 4);
        }
        unsigned pk[4];
        pk[0] = pack_bf16(f0.x, f0.y);
        pk[1] = pack_bf16(f0.z, f0.w);
        pk[2] = pack_bf16(f1.x, f1.y);
        pk[3] = pack_bf16(f1.z, f1.w);
        af[kc] = *(short8*)pk;
    }
#pragma unroll
    for (int kc = 0; kc < 4; ++kc) {
#pragma unroll
        for (int n = 0; n < 8; ++n) {
            short8 bf = *(const short8*)&wtb[(size_t)(((n << 4) + c) * 128 + (kc << 5) + (grp << 3))];
            acc[n] = __builtin_amdgcn_mfma_f32_16x16x32_bf16(af[kc], bf, acc[n], 0, 0, 0);
        }
    }
}

// ---------------- MFMA GEMM (W layers): xp = bf16(h) @ W; epilogue xpk + es/ed.
// Block 0 also maintains the dummy row NN (pads: w = exp(-1e30...) = 0, xpk row = 0).
__global__ __launch_bounds__(256) void gemm_mfma_kernel(const float* __restrict__ H,
                                                        const unsigned short* __restrict__ wtb,
                                                        unsigned* __restrict__ XP,
                                                        const float* __restrict__ a_s,
                                                        const float* __restrict__ a_d,
                                                        float* __restrict__ es,
                                                        float* __restrict__ ed, int M) {
    int t = threadIdx.x;
    int w = t >> 6, l = t & 63;
    int c = l & 15, grp = l >> 4;
    int i0 = blockIdx.x * 64 + w * 16;
    int arow = i0 + c;

    if (blockIdx.x == 0) {
        if (t < 64) XP[(size_t)NN * 64 + t] = 0u;
        else if (t < 68) es[(size_t)NN * 4 + (t - 64)] = -1e30f;
    }

    floatx4 acc[8];
    mfma_core(H, arow, arow < M, wtb, c, grp, acc);

    float asv[8], adv[8];
#pragma unroll
    for (int n = 0; n < 8; ++n) { asv[n] = a_s[(n << 4) + c]; adv[n] = a_d[(n << 4) + c]; }

    float sp[4][4], dp[4][4];   // [r][head]
#pragma unroll
    for (int r = 0; r < 4; ++r)
#pragma unroll
        for (int hd = 0; hd < 4; ++hd) { sp[r][hd] = 0.f; dp[r][hd] = 0.f; }

#pragma unroll
    for (int n = 0; n < 8; ++n) {
#pragma unroll
        for (int r = 0; r < 4; ++r) {
            float vv = acc[n][r];
            float pv = __shfl_xor(vv, 1);
            int row = i0 + (grp << 2) + r;
            if (!(c & 1) && row < M)
                XP[(size_t)row * 64 + (n << 3) + (c >> 1)] = pack_bf16(vv, pv);
            sp[r][n >> 1] = fmaf(vv, asv[n], sp[r][n >> 1]);
            dp[r][n >> 1] = fmaf(vv, adv[n], dp[r][n >> 1]);
        }
    }
#pragma unroll
    for (int r = 0; r < 4; ++r)
#pragma unroll
        for (int hd = 0; hd < 4; ++hd) {
            float s = sp[r][hd], d = dp[r][hd];
#pragma unroll
            for (int off = 1; off <= 8; off <<= 1) {
                s += __shfl_xor(s, off);
                d += __shfl_xor(d, off);
            }
            sp[r][hd] = s; dp[r][hd] = d;
        }
    if (c < 4) {
#pragma unroll
        for (int r = 0; r < 4; ++r) {
            int row = i0 + (grp << 2) + r;
            if (row < M) {
                float s = (c == 0) ? sp[r][0] : (c == 1) ? sp[r][1] : (c == 2) ? sp[r][2] : sp[r][3];
                float d = (c == 0) ? dp[r][0] : (c == 1) ? dp[r][1] : (c == 2) ? dp[r][2] : dp[r][3];
                es[(size_t)row * 4 + c] = s;
                ed[(size_t)row * 4 + c] = d;
            }
        }
    }
}

// ---------------- MFMA heads: layer1 via MFMA (128 virtual cols), layer2 in epilogue ----------------
__global__ __launch_bounds__(256) void gemm_mfma_heads_kernel(const float* __restrict__ H,
                                                              const unsigned short* __restrict__ wtb,
                                                              const float* __restrict__ ib1,
                                                              const float* __restrict__ tb1,
                                                              const float* __restrict__ iw2,
                                                              const float* __restrict__ ib2,
                                                              const float* __restrict__ tw2,
                                                              const float* __restrict__ tb2,
                                                              float* __restrict__ out, int M) {
    int t = threadIdx.x;
    int w = t >> 6, l = t & 63;
    int c = l & 15, grp = l >> 4;
    int i0 = blockIdx.x * 64 + w * 16;
    int arow = i0 + c;

    floatx4 acc[8];
    mfma_core(H, arow, arow < M, wtb, c, grp, acc);

    float iw2v[4][3], tw2v[4][2], ib1v[4], tb1v[4];
#pragma unroll
    for (int n = 0; n < 4; ++n) {
        int lc = (n << 4) + c;
        ib1v[n] = ib1[lc];
        tb1v[n] = tb1[lc];
#pragma unroll
        for (int o = 0; o < 3; ++o) iw2v[n][o] = iw2[lc * 3 + o];
#pragma unroll
        for (int d = 0; d < 2; ++d) tw2v[n][d] = tw2[lc * 2 + d];
    }

    float pi[4][3], pt[4][2];
#pragma unroll
    for (int r = 0; r < 4; ++r) {
#pragma unroll
        for (int o = 0; o < 3; ++o) pi[r][o] = 0.f;
#pragma unroll
        for (int d = 0; d < 2; ++d) pt[r][d] = 0.f;
    }
#pragma unroll
    for (int n = 0; n < 4; ++n)
#pragma unroll
        for (int r = 0; r < 4; ++r) {
            float vi = acc[n][r] + ib1v[n];     vi = vi > 0.f ? vi : 0.f;
            float vt = acc[n + 4][r] + tb1v[n]; vt = vt > 0.f ? vt : 0.f;
#pragma unroll
            for (int o = 0; o < 3; ++o) pi[r][o] = fmaf(vi, iw2v[n][o], pi[r][o]);
#pragma unroll
            for (int d = 0; d < 2; ++d) pt[r][d] = fmaf(vt, tw2v[n][d], pt[r][d]);
        }
#pragma unroll
    for (int r = 0; r < 4; ++r) {
#pragma unroll
        for (int o = 0; o < 3; ++o) {
            float s = pi[r][o];
#pragma unroll
            for (int off = 1; off <= 8; off <<= 1) s += __shfl_xor(s, off);
            pi[r][o] = s;
        }
#pragma unroll
        for (int d = 0; d < 2; ++d) {
            float s = pt[r][d];
#pragma unroll
            for (int off = 1; off <= 8; off <<= 1) s += __shfl_xor(s, off);
            pt[r][d] = s;
        }
    }
    if (c == 0) {
#pragma unroll
        for (int r = 0; r < 4; ++r) {
            int row = i0 + (grp << 2) + r;
            if (row < M) {
#pragma unroll
                for (int o = 0; o < 3; ++o) out[(size_t)row * 3 + o] = pi[r][o] + ib2[o];
#pragma unroll
                for (int d = 0; d < 2; ++d) {
                    float a = pt[r][d] + tb2[d];
                    float sp = a > 20.f ? a : log1pf(__expf(a));
                    out[(size_t)(NN * 3) + (size_t)row * 2 + d] = sp;
                }
            }
        }
    }
}

// ---------------- gat (v17 padded-CSR form; at its gather-pattern floor) ----------------
__global__ __launch_bounds__(256, 6) void gat_kernel(const unsigned* __restrict__ xpk,
                                                     const float* __restrict__ es,
                                                     const float* __restrict__ ed,
                                                     const unsigned* __restrict__ rowdesc,
                                                     const int* __restrict__ colidx,
                                                     float* __restrict__ h,   // in-out (residual)
                                                     const float* __restrict__ bc,
                                                     const float* __restrict__ g,
                                                     const float* __restrict__ be) {
    int wv = threadIdx.x >> 6, l = threadIdx.x & 63;
    int hf = l >> 5;                        // which node of the pair
    int lh = l & 31;
    int hd = lh >> 3;                       // head 0..3
    int j  = lh & 7;                        // 0..7
    int v = blockIdx.x * 8 + wv * 2 + hf;   // grid covers NN exactly (6250*8=50000)
    if (v >= NN) return;                    // defensive
    unsigned dsc = rowdesc[v];
    int s0 = (int)(dsc & 0xFFFFFFu);
    int alen = (int)(dsc >> 24) << 3;       // padded length, multiple of 8, >= 8
    int c0 = (hd << 5) + (j << 2);          // 4 channels owned by this lane
    int xsel = (hd << 4) + (j << 1);        // even dword index into 64-dword xpk row
    float edv = ed[((unsigned)v << 2) + hd];

    float4 h4 = *(const float4*)&h[(size_t)v * 128 + c0];

    float a0 = 0.f, a1 = 0.f, a2 = 0.f, a3 = 0.f, den = 0.f;
    for (int p8 = 0; p8 < alen; p8 += 8) {  // divergent between halves: exec-masked
        int u[8];
#pragma unroll
        for (int q = 0; q < 8; ++q) u[q] = colidx[s0 + p8 + q];
        uint2 xw[8];
#pragma unroll
        for (int q = 0; q < 8; ++q)
            xw[q] = *(const uint2*)&xpk[((unsigned)u[q] << 6) + xsel];
        float w[8];
#pragma unroll
        for (int q = 0; q < 8; ++q) {
            float e = es[((unsigned)u[q] << 2) + hd] + edv;
            e = fmaxf(e, 0.2f * e);         // leaky_relu, slope<1 => max form
            w[q] = __expf(e);               // pads: exp(-huge) = exactly 0
            den += w[q];
        }
#pragma unroll
        for (int q = 0; q < 8; ++q) {
            float2 x0 = unpack_bf16(xw[q].x);
            float2 x1 = unpack_bf16(xw[q].y);
            a0 = fmaf(w[q], x0.x, a0);
            a1 = fmaf(w[q], x0.y, a1);
            a2 = fmaf(w[q], x1.x, a2);
            a3 = fmaf(w[q], x1.y, a3);
        }
    }
    float rd = 1.f / den;

    float4 bc4 = *(const float4*)&bc[c0];
    float y0 = a0 * rd + bc4.x + h4.x;
    float y1 = a1 * rd + bc4.y + h4.y;
    float y2 = a2 * rd + bc4.z + h4.z;
    float y3 = a3 * rd + bc4.w + h4.w;

    float s = y0 + y1 + y2 + y3;
#pragma unroll
    for (int off = 16; off >= 1; off >>= 1) s += __shfl_xor(s, off);
    float mean = s * (1.f / 128.f);
    float d0 = y0 - mean, d1 = y1 - mean, d2 = y2 - mean, d3 = y3 - mean;
    float vv = d0 * d0 + d1 * d1 + d2 * d2 + d3 * d3;
#pragma unroll
    for (int off = 16; off >= 1; off >>= 1) vv += __shfl_xor(vv, off);
    float rstd = rsqrtf(vv * (1.f / 128.f) + 1e-5f);
    float4 g4  = *(const float4*)&g[c0];
    float4 be4 = *(const float4*)&be[c0];
    float z0 = d0 * rstd * g4.x + be4.x;
    float z1 = d1 * rstd * g4.y + be4.y;
    float z2 = d2 * rstd * g4.z + be4.z;
    float z3 = d3 * rstd * g4.w + be4.w;
    float4 o;
    o.x = z0 > 0.f ? z0 : 0.f;
    o.y = z1 > 0.f ? z1 : 0.f;
    o.z = z2 > 0.f ? z2 : 0.f;
    o.w = z3 > 0.f ? z3 : 0.f;
    *(float4*)&h[(size_t)v * 128 + c0] = o;   // all 64 lanes write (2 rows per wave)
}

extern "C" void kernel_launch(void* const* d_in, const int* in_sizes, int n_in,
                              void* d_out, int out_size, void* d_ws, size_t ws_size,
                              hipStream_t stream) {
    const float* x      = (const float*)d_in[0];
    const int*   ei     = (const int*)d_in[1];
    const float* enc_w1 = (const float*)d_in[2];
    const float* enc_b1 = (const float*)d_in[3];
    const float* enc_w2 = (const float*)d_in[4];
    const float* enc_b2 = (const float*)d_in[5];
    const float *W[3], *as_[3], *ad_[3], *bc[3], *g[3], *be[3];
    for (int l = 0; l < 3; ++l) {
        W[l]   = (const float*)d_in[6 + l * 6 + 0];
        as_[l] = (const float*)d_in[6 + l * 6 + 1];
        ad_[l] = (const float*)d_in[6 + l * 6 + 2];
        bc[l]  = (const float*)d_in[6 + l * 6 + 3];
        g[l]   = (const float*)d_in[6 + l * 6 + 4];
        be[l]  = (const float*)d_in[6 + l * 6 + 5];
    }
    const float* imp_w1 = (const float*)d_in[24];
    const float* imp_b1 = (const float*)d_in[25];
    const float* imp_w2 = (const float*)d_in[26];
    const float* imp_b2 = (const float*)d_in[27];
    const float* tim_w1 = (const float*)d_in[28];
    const float* tim_b1 = (const float*)d_in[29];
    const float* tim_w2 = (const float*)d_in[30];
    const float* tim_b2 = (const float*)d_in[31];

    int* gcursor = (int*)d_ws;                             // NPART (+64 pad)
    unsigned* rowdesc = (unsigned*)(gcursor + NPART + 64); // NN
    int* colidx = (int*)(rowdesc + NN);                    // NPART*PCAP_PAD (8.7 MB)
    uintptr_t pb = (uintptr_t)(colidx + (size_t)NPART * PCAP_PAD);
    pb = (pb + 255) & ~(uintptr_t)255;
    unsigned* pbuf = (unsigned*)pb;          // NPART*PCAP (7.3 MB)
    uintptr_t fb = (uintptr_t)(pbuf + (size_t)NPART * PCAP);
    fb = (fb + 255) & ~(uintptr_t)255;
    float* es = (float*)fb;                  // (NN+1)*4 (+pad)
    float* ed = es + (size_t)NN * 4 + 64;    // NN*4
    float* h  = ed + (size_t)NN * 4;         // NN*128 fp32
    float* xpf = h + (size_t)NN * 128;       // region sized NN*128 floats
    unsigned* xpk = (unsigned*)xpf;          // packed bf16 xp, (NN+1)*64 dwords
    unsigned short* wtb = (unsigned short*)(xpf + (size_t)NN * 128); // 5 x 16384 bf16 (160 KB)

    hipMemsetAsync(gcursor, 0, NPART * sizeof(int), stream);
    pass1_kernel<<<512, 1024, 0, stream>>>(ei, gcursor, pbuf);
    pass2_kernel<<<NPART, 1024, 0, stream>>>(pbuf, gcursor, rowdesc, colidx,
                                             W[0], W[1], W[2], enc_w2, imp_w1, tim_w1, wtb);

    const int GB64 = (NN + 63) / 64;
    gemm_enc_fused_kernel<<<GB64, 256, 0, stream>>>(x, enc_w1, enc_b1,
                                                    wtb + (size_t)3 * 16384, enc_b2, h, NN);

    for (int l = 0; l < 3; ++l) {
        gemm_mfma_kernel<<<GB64, 256, 0, stream>>>(h, wtb + (size_t)l * 16384, xpk,
                                                   as_[l], ad_[l], es, ed, NN);
        gat_kernel<<<(NN + 7) / 8, 256, 0, stream>>>(xpk, es, ed, rowdesc, colidx, h,
                                                     bc[l], g[l], be[l]);
    }

    gemm_mfma_heads_kernel<<<GB64, 256, 0, stream>>>(h, wtb + (size_t)4 * 16384,
                                                     imp_b1, tim_b1, imp_w2, imp_b2,
                                                     tim_w2, tim_b2, (float*)d_out, NN);
}